// Round 2
// baseline (376.770 us; speedup 1.0000x reference)
//
#include <hip/hip_runtime.h>
#include <hip/hip_bf16.h>
#include <stdint.h>

#define D 128
#define K 8
#define BGRAPH 64
#define CH 64    // edges per wave in gine_reduce
#define GRP 4    // edges per inner group

typedef __attribute__((ext_vector_type(8))) short bf16x8;
typedef __attribute__((ext_vector_type(4))) float f32x4;
typedef __attribute__((ext_vector_type(2))) float f32x2;

__device__ __forceinline__ short f2bf(float f) {
    union { float f; uint32_t u; } v; v.f = f;
    const uint32_t r = (v.u + 0x7fffu + ((v.u >> 16) & 1u)) >> 16;
    return (short)r;
}
__device__ __forceinline__ float bflo(uint32_t u) {
    union { uint32_t u; float f; } v; v.u = u << 16; return v.f;
}
__device__ __forceinline__ float bfhi(uint32_t u) {
    union { uint32_t u; float f; } v; v.u = u & 0xffff0000u; return v.f;
}

// ---------------------------------------------------------------------------
// Stage 0 (fused prep): cast x->bf16, ea->bf16, W1/W2->bf16 transposed,
// and dst in-degree histogram. Disjoint blockIdx ranges.
// ---------------------------------------------------------------------------
__global__ __launch_bounds__(256) void prep_kernel(
    const float* __restrict__ x, const float* __restrict__ ea,
    const float* __restrict__ W1, const float* __restrict__ W2,
    const int* __restrict__ dst,
    __hip_bfloat16* __restrict__ xb, short* __restrict__ eab,
    short* __restrict__ wb1t, short* __restrict__ wb2t,
    int* __restrict__ deg,
    int NX, int NEA, int E, int NBX, int NBE, int NBW)
{
    const int b = blockIdx.x;
    const int t = threadIdx.x;
    if (b < NBX) {
        // ---- cast x (8 floats/thread) ----
        const int i = b * 2048 + t * 8;
        if (i + 8 <= NX) {
            const float4 a = *(const float4*)(x + i);
            const float4 c = *(const float4*)(x + i + 4);
            short v[8];
            v[0] = f2bf(a.x); v[1] = f2bf(a.y); v[2] = f2bf(a.z); v[3] = f2bf(a.w);
            v[4] = f2bf(c.x); v[5] = f2bf(c.y); v[6] = f2bf(c.z); v[7] = f2bf(c.w);
            *(uint4*)((short*)xb + i) = *(const uint4*)v;
        }
    } else if (b < NBX + NBE) {
        // ---- cast ea (8 floats/thread) ----
        const int i = (b - NBX) * 2048 + t * 8;
        if (i + 8 <= NEA) {
            const float4 a = *(const float4*)(ea + i);
            const float4 c = *(const float4*)(ea + i + 4);
            short v[8];
            v[0] = f2bf(a.x); v[1] = f2bf(a.y); v[2] = f2bf(a.z); v[3] = f2bf(a.w);
            v[4] = f2bf(c.x); v[5] = f2bf(c.y); v[6] = f2bf(c.z); v[7] = f2bf(c.w);
            *(uint4*)(eab + i) = *(const uint4*)v;
        }
    } else if (b < NBX + NBE + NBW) {
        // ---- W transpose cast (1 elem/thread) ----
        const int idx = (b - NBX - NBE) * 256 + t;
        const int which = idx >> 14;           // 0: W1, 1: W2
        const int rem = idx & 16383;
        const int n = rem >> 7;
        const int k = rem & 127;
        const float* W = which ? W2 : W1;
        short* O = which ? wb2t : wb1t;
        O[n * D + k] = f2bf(W[(size_t)k * D + n]);
    } else {
        // ---- dst histogram (4 edges/thread) ----
        const int i = ((b - NBX - NBE - NBW) * 256 + t) * 4;
        if (i + 4 <= E) {
            const int4 v = *(const int4*)(dst + i);
            atomicAdd(&deg[v.x], 1);
            atomicAdd(&deg[v.y], 1);
            atomicAdd(&deg[v.z], 1);
            atomicAdd(&deg[v.w], 1);
        } else {
            for (int j = i; j < E; ++j) atomicAdd(&deg[dst[j]], 1);
        }
    }
}

// ---------------------------------------------------------------------------
// Stage 1b: three-phase exclusive scan of deg[N] -> cursor[N]
// ---------------------------------------------------------------------------
__global__ __launch_bounds__(256) void scan_partial_kernel(
    const int* __restrict__ deg, int* __restrict__ bsum, int N)
{
    const int t = threadIdx.x;
    const int base = (blockIdx.x * 256 + t) * 4;
    int s = 0;
    if (base + 4 <= N) {
        const int4 v = *(const int4*)(deg + base);
        s = v.x + v.y + v.z + v.w;
    } else {
        for (int j = base; j < N; ++j) s += deg[j];
    }
    __shared__ int red[256];
    red[t] = s;
    __syncthreads();
    for (int off = 128; off; off >>= 1) {
        if (t < off) red[t] += red[t + off];
        __syncthreads();
    }
    if (t == 0) bsum[blockIdx.x] = red[0];
}

__global__ __launch_bounds__(64) void scan_top_kernel(
    const int* __restrict__ bsum, int* __restrict__ boffs, int nb)
{
    __shared__ int sh[64];
    const int t = threadIdx.x;
    const int v = (t < nb) ? bsum[t] : 0;
    sh[t] = v;
    __syncthreads();
    for (int off = 1; off < 64; off <<= 1) {
        const int u = (t >= off) ? sh[t - off] : 0;
        __syncthreads();
        sh[t] += u;
        __syncthreads();
    }
    if (t < nb) boffs[t] = sh[t] - v;      // exclusive
}

__global__ __launch_bounds__(256) void scan_final_kernel(
    const int* __restrict__ deg, const int* __restrict__ boffs,
    int* __restrict__ cursor, int N)
{
    const int t = threadIdx.x;
    const int base = (blockIdx.x * 256 + t) * 4;
    int v0 = 0, v1 = 0, v2 = 0, v3 = 0;
    if (base + 4 <= N) {
        const int4 v = *(const int4*)(deg + base);
        v0 = v.x; v1 = v.y; v2 = v.z; v3 = v.w;
    } else {
        if (base     < N) v0 = deg[base];
        if (base + 1 < N) v1 = deg[base + 1];
        if (base + 2 < N) v2 = deg[base + 2];
        if (base + 3 < N) v3 = deg[base + 3];
    }
    const int s = v0 + v1 + v2 + v3;
    __shared__ int sh[256];
    sh[t] = s;
    __syncthreads();
    for (int off = 1; off < 256; off <<= 1) {
        const int u = (t >= off) ? sh[t - off] : 0;
        __syncthreads();
        sh[t] += u;
        __syncthreads();
    }
    int ex = boffs[blockIdx.x] + sh[t] - s;
    if (base < N)     { cursor[base]     = ex; } ex += v0;
    if (base + 1 < N) { cursor[base + 1] = ex; } ex += v1;
    if (base + 2 < N) { cursor[base + 2] = ex; } ex += v2;
    if (base + 3 < N) { cursor[base + 3] = ex; }
}

// ---------------------------------------------------------------------------
// Stage 1c: scatter packed (src|dst<<16, eid) into dst-grouped order
// ---------------------------------------------------------------------------
__global__ __launch_bounds__(256) void scatter_kernel(
    const int* __restrict__ src, const int* __restrict__ dst,
    int* __restrict__ cursor, uint2* __restrict__ md, int E)
{
    const int i = blockIdx.x * 256 + threadIdx.x;
    if (i < E) {
        const unsigned sv = (unsigned)src[i];
        const unsigned dv = (unsigned)dst[i];
        const int p = atomicAdd(&cursor[dv], 1);
        md[p] = make_uint2(sv | (dv << 16), (unsigned)i);
    }
}

// ---------------------------------------------------------------------------
// Stage 1d: edge-parallel gather-reduce. Packed scalar metadata (uniform ->
// SGPR), bf16 scalar ea rows (SALU unpack), bf16 x gathers, packed f32x2
// v_pk_fma math. Pipeline: meta 3 groups ahead, x 2 ahead, ea 1 ahead.
// ---------------------------------------------------------------------------
__device__ __forceinline__ void flush_row(
    float* __restrict__ agg, int node, int d, f32x2 acc, int first, int last)
{
    float* p = agg + (size_t)node * D + d;
    if (node == first || node == last) {
        if (acc.x != 0.f) atomicAdd(p,     acc.x);
        if (acc.y != 0.f) atomicAdd(p + 1, acc.y);
    } else {
        *(f32x2*)p = acc;
    }
}

__global__ __launch_bounds__(256) void gine_reduce_kernel(
    const __hip_bfloat16* __restrict__ xb, const uint2* __restrict__ md,
    const short* __restrict__ eab, const float* __restrict__ We,
    const float* __restrict__ be, float* __restrict__ agg, int E)
{
    const int wave = threadIdx.x >> 6;
    const int lane = threadIdx.x & 63;
    const int chunk = __builtin_amdgcn_readfirstlane(blockIdx.x * 4 + wave);
    const int e0 = chunk * CH;
    if (e0 >= E) return;
    const int d = lane * 2;
    const int NG = CH / GRP;

    f32x2 w[16];
    #pragma unroll
    for (int j = 0; j < 16; ++j) w[j] = *(const f32x2*)(We + j * D + d);
    const f32x2 bb = *(const f32x2*)(be + d);

    // prologue: meta groups 0,1,2; ea group 0; x groups 0,1
    uint2 ma[GRP], mb[GRP], mc[GRP];
    #pragma unroll
    for (int j = 0; j < GRP; ++j) ma[j] = md[e0 + j];
    #pragma unroll
    for (int j = 0; j < GRP; ++j) mb[j] = md[e0 + GRP + j];
    #pragma unroll
    for (int j = 0; j < GRP; ++j) mc[j] = md[e0 + 2 * GRP + j];

    uint4 ea0[GRP][2];
    #pragma unroll
    for (int j = 0; j < GRP; ++j) {
        const uint4* p = (const uint4*)(eab + (size_t)ma[j].y * 16);
        ea0[j][0] = p[0]; ea0[j][1] = p[1];
    }
    uint32_t xcur[GRP], xn1[GRP];
    #pragma unroll
    for (int j = 0; j < GRP; ++j)
        xcur[j] = *(const uint32_t*)(xb + (size_t)(ma[j].x & 0xffffu) * D + d);
    #pragma unroll
    for (int j = 0; j < GRP; ++j)
        xn1[j] = *(const uint32_t*)(xb + (size_t)(mb[j].x & 0xffffu) * D + d);

    const int first = (int)(ma[0].x >> 16);
    const int last  = (int)(md[e0 + CH - 1].x >> 16);

    f32x2 acc = {0.f, 0.f};
    int cur = first;

    for (int g = 0; g < NG; ++g) {
        // prefetch: meta g+3, ea g+1, x g+2
        uint2 mnew[GRP] = {};
        uint4 ean[GRP][2] = {};
        uint32_t xn2[GRP] = {};
        if (g + 3 < NG) {
            #pragma unroll
            for (int j = 0; j < GRP; ++j) mnew[j] = md[e0 + (g + 3) * GRP + j];
        }
        if (g + 1 < NG) {
            #pragma unroll
            for (int j = 0; j < GRP; ++j) {
                const uint4* p = (const uint4*)(eab + (size_t)mb[j].y * 16);
                ean[j][0] = p[0]; ean[j][1] = p[1];
            }
        }
        if (g + 2 < NG) {
            #pragma unroll
            for (int j = 0; j < GRP; ++j)
                xn2[j] = *(const uint32_t*)(xb + (size_t)(mc[j].x & 0xffffu) * D + d);
        }

        #pragma unroll
        for (int j = 0; j < GRP; ++j) {
            const int dk = (int)(ma[j].x >> 16);
            if (dk != cur) {                  // wave-uniform scalar branch
                flush_row(agg, cur, d, acc, first, last);
                acc.x = 0.f; acc.y = 0.f;
                cur = dk;
            }
            const uint32_t xu = xcur[j];
            f32x2 m;
            m.x = bb.x + bflo(xu);
            m.y = bb.y + bfhi(xu);
            const uint4 ua = ea0[j][0];
            const uint4 ub = ea0[j][1];
            const uint32_t ud[8] = {ua.x, ua.y, ua.z, ua.w,
                                    ub.x, ub.y, ub.z, ub.w};
            #pragma unroll
            for (int t = 0; t < 8; ++t) {
                const float a0 = bflo(ud[t]);   // uniform -> SALU
                const float a1 = bfhi(ud[t]);
                const f32x2 av0 = {a0, a0};     // uniform splat -> SGPR pair
                const f32x2 av1 = {a1, a1};
                m += av0 * w[2 * t];            // v_pk_fma_f32 (contracted)
                m += av1 * w[2 * t + 1];
            }
            f32x2 r;
            r.x = m.x > 0.f ? m.x : 0.f;
            r.y = m.y > 0.f ? m.y : 0.f;
            acc += r;
        }

        #pragma unroll
        for (int j = 0; j < GRP; ++j) {
            ma[j] = mb[j]; mb[j] = mc[j]; mc[j] = mnew[j];
            ea0[j][0] = ean[j][0]; ea0[j][1] = ean[j][1];
            xcur[j] = xn1[j]; xn1[j] = xn2[j];
        }
    }
    flush_row(agg, cur, d, acc, first, last);
}

// ---------------------------------------------------------------------------
// Stage 2: MFMA MLP.  x_res = relu(h@W1+b1)@W2+b2,  h = (1+eps)*x + agg.
// Block = 64 rows, 4 waves; wave owns 16 rows; t overwrites h in place.
// ---------------------------------------------------------------------------
#define MROWS 64
#define HSTR  132
__global__ __launch_bounds__(256) void mlp_mfma_kernel(
    const float* __restrict__ x, const float* __restrict__ agg,
    const float* __restrict__ epsp,
    const short* __restrict__ wb1t, const float* __restrict__ b1,
    const short* __restrict__ wb2t, const float* __restrict__ b2,
    float* __restrict__ xres, int N)
{
    __shared__ float hsh[MROWS * HSTR];   // 33.8 KB
    const int row0 = blockIdx.x * MROWS;
    const float ep = 1.0f + epsp[0];

    for (int i = threadIdx.x; i < MROWS * D / 4; i += 256) {
        const int flat = i * 4;
        const int r = flat >> 7;
        const int c = flat & (D - 1);
        const int row = row0 + r;
        float4 hv = make_float4(0.f, 0.f, 0.f, 0.f);
        if (row < N) {
            const float4 xv = *(const float4*)(x   + (size_t)row * D + c);
            const float4 av = *(const float4*)(agg + (size_t)row * D + c);
            hv = make_float4(ep * xv.x + av.x, ep * xv.y + av.y,
                             ep * xv.z + av.z, ep * xv.w + av.w);
        }
        *(float4*)(hsh + r * HSTR + c) = hv;
    }
    __syncthreads();

    const int lane = threadIdx.x & 63;
    const int wrow = (threadIdx.x >> 6) * 16;  // wave's 16-row window
    const int m = lane & 15;
    const int q = lane >> 4;

    f32x4 acc[8];

    // ---- layer 1 ----
    #pragma unroll
    for (int ct = 0; ct < 8; ++ct) {
        const float b = b1[ct * 16 + m];
        acc[ct] = (f32x4){b, b, b, b};
    }
    #pragma unroll
    for (int ks = 0; ks < 4; ++ks) {
        const float* ap = hsh + (wrow + m) * HSTR + ks * 32 + q * 8;
        float av[8];
        *(float4*)(av)     = *(const float4*)ap;
        *(float4*)(av + 4) = *(const float4*)(ap + 4);
        bf16x8 a;
        #pragma unroll
        for (int j = 0; j < 8; ++j) a[j] = f2bf(av[j]);
        #pragma unroll
        for (int ct = 0; ct < 8; ++ct) {
            const bf16x8 b = *(const bf16x8*)(wb1t + (ct * 16 + m) * D + ks * 32 + q * 8);
            acc[ct] = __builtin_amdgcn_mfma_f32_16x16x32_bf16(a, b, acc[ct], 0, 0, 0);
        }
    }
    #pragma unroll
    for (int ct = 0; ct < 8; ++ct)
        #pragma unroll
        for (int r = 0; r < 4; ++r) {
            const float v = acc[ct][r];
            hsh[(wrow + q * 4 + r) * HSTR + ct * 16 + m] = v > 0.f ? v : 0.f;
        }

    // ---- layer 2 ----
    #pragma unroll
    for (int ct = 0; ct < 8; ++ct) {
        const float b = b2[ct * 16 + m];
        acc[ct] = (f32x4){b, b, b, b};
    }
    #pragma unroll
    for (int ks = 0; ks < 4; ++ks) {
        const float* ap = hsh + (wrow + m) * HSTR + ks * 32 + q * 8;
        float av[8];
        *(float4*)(av)     = *(const float4*)ap;
        *(float4*)(av + 4) = *(const float4*)(ap + 4);
        bf16x8 a;
        #pragma unroll
        for (int j = 0; j < 8; ++j) a[j] = f2bf(av[j]);
        #pragma unroll
        for (int ct = 0; ct < 8; ++ct) {
            const bf16x8 b = *(const bf16x8*)(wb2t + (ct * 16 + m) * D + ks * 32 + q * 8);
            acc[ct] = __builtin_amdgcn_mfma_f32_16x16x32_bf16(a, b, acc[ct], 0, 0, 0);
        }
    }
    #pragma unroll
    for (int r = 0; r < 4; ++r) {
        const int row = row0 + wrow + q * 4 + r;
        if (row < N) {
            #pragma unroll
            for (int ct = 0; ct < 8; ++ct)
                xres[(size_t)row * D + ct * 16 + m] = acc[ct][r];
        }
    }
}

// ---------------------------------------------------------------------------
// Stage 3: per-(graph,pocket) masked sums
// ---------------------------------------------------------------------------
#define PPARTS 32
__global__ __launch_bounds__(128) void pocket_sum_kernel(
    const float* __restrict__ xres, const float* __restrict__ pmask,
    const int* __restrict__ batch,
    float* __restrict__ psum, float* __restrict__ pcnt, int N)
{
    const int g = blockIdx.x / PPARTS;
    const int part = blockIdx.x % PPARTS;

    int lo, hi;
    {
        int l = 0, r = N;
        while (l < r) { int m = (l + r) >> 1; if (batch[m] < g) l = m + 1; else r = m; }
        lo = l;
        r = N;
        while (l < r) { int m = (l + r) >> 1; if (batch[m] < g + 1) l = m + 1; else r = m; }
        hi = l;
    }
    const int cnt = hi - lo;
    const int per = (cnt + PPARTS - 1) / PPARTS;
    const int s = lo + part * per;
    const int e = min(s + per, hi);

    const int d = threadIdx.x;
    float acc[K];
    #pragma unroll
    for (int k = 0; k < K; ++k) acc[k] = 0.0f;
    float c = 0.0f;

    for (int n = s; n < e; ++n) {
        const float xv = xres[(size_t)n * D + d];
        const float4 m0 = *(const float4*)(pmask + (size_t)n * K);
        const float4 m1 = *(const float4*)(pmask + (size_t)n * K + 4);
        acc[0] += m0.x * xv; acc[1] += m0.y * xv;
        acc[2] += m0.z * xv; acc[3] += m0.w * xv;
        acc[4] += m1.x * xv; acc[5] += m1.y * xv;
        acc[6] += m1.z * xv; acc[7] += m1.w * xv;
        if (d < K) c += pmask[(size_t)n * K + d];
    }
    #pragma unroll
    for (int k = 0; k < K; ++k)
        atomicAdd(&psum[(size_t)g * (K * D) + k * D + d], acc[k]);
    if (d < K) atomicAdd(&pcnt[g * K + d], c);
}

// ---------------------------------------------------------------------------
// Stage 4: pocket_emb = (psum / (pcnt + 1e-9)) @ Wv + bv
// ---------------------------------------------------------------------------
__global__ __launch_bounds__(128) void pocket_emb_kernel(
    const float* __restrict__ psum, const float* __restrict__ pcnt,
    const float* __restrict__ Wv, const float* __restrict__ bv,
    float* __restrict__ pemb)
{
    __shared__ float smean[K * D];
    __shared__ float scnt[K];
    const int g = blockIdx.x;
    const int d = threadIdx.x;
    if (d < K) scnt[d] = pcnt[g * K + d];
    __syncthreads();
    #pragma unroll
    for (int k = 0; k < K; ++k)
        smean[k * D + d] = psum[(size_t)g * (K * D) + k * D + d] / (scnt[k] + 1e-9f);
    __syncthreads();

    float acc[K];
    const float bvv = bv[d];
    #pragma unroll
    for (int k = 0; k < K; ++k) acc[k] = bvv;
    for (int j = 0; j < D; ++j) {
        const float w = Wv[j * D + d];
        #pragma unroll
        for (int k = 0; k < K; ++k) acc[k] += smean[k * D + j] * w;
    }
    #pragma unroll
    for (int k = 0; k < K; ++k)
        pemb[(size_t)g * (K * D) + k * D + d] = acc[k];
}

// ---------------------------------------------------------------------------
// Stage 5: feedback gather + LayerNorm + ReLU. One wave per node.
// ---------------------------------------------------------------------------
__global__ __launch_bounds__(256) void ln_kernel(
    const float* __restrict__ xres, const float* __restrict__ pmask,
    const int* __restrict__ batch, const float* __restrict__ pemb,
    const float* __restrict__ gamma, const float* __restrict__ beta,
    float* __restrict__ out, int N)
{
    const int wave = threadIdx.x >> 6;
    const int lane = threadIdx.x & 63;
    const int n = blockIdx.x * 4 + wave;
    if (n >= N) return;
    const int d = lane * 2;

    float2 v = *(const float2*)(xres + (size_t)n * D + d);
    const int g = batch[n];
    const float* pe = pemb + (size_t)g * (K * D);
    const float4 m0 = *(const float4*)(pmask + (size_t)n * K);
    const float4 m1 = *(const float4*)(pmask + (size_t)n * K + 4);
    const float mk[K] = {m0.x, m0.y, m0.z, m0.w, m1.x, m1.y, m1.z, m1.w};
    #pragma unroll
    for (int k = 0; k < K; ++k) {
        if (mk[k] != 0.0f) {   // wave-uniform branch
            const float2 p = *(const float2*)(pe + k * D + d);
            v.x += mk[k] * p.x;
            v.y += mk[k] * p.y;
        }
    }

    float s = v.x + v.y;
    #pragma unroll
    for (int off = 32; off; off >>= 1) s += __shfl_xor(s, off, 64);
    const float mu = s * (1.0f / 128.0f);
    const float d0 = v.x - mu, d1 = v.y - mu;
    float sq = d0 * d0 + d1 * d1;
    #pragma unroll
    for (int off = 32; off; off >>= 1) sq += __shfl_xor(sq, off, 64);
    const float var = sq * (1.0f / 128.0f);
    const float inv = rsqrtf(var + 1e-5f);

    const float2 gm = *(const float2*)(gamma + d);
    const float2 bt = *(const float2*)(beta + d);
    float y0 = d0 * inv * gm.x + bt.x;
    float y1 = d1 * inv * gm.y + bt.y;
    y0 = y0 > 0.0f ? y0 : 0.0f;
    y1 = y1 > 0.0f ? y1 : 0.0f;
    *(float2*)(out + (size_t)n * D + d) = make_float2(y0, y1);
}

// ---------------------------------------------------------------------------
extern "C" void kernel_launch(void* const* d_in, const int* in_sizes, int n_in,
                              void* d_out, int out_size, void* d_ws, size_t ws_size,
                              hipStream_t stream)
{
    const float* x     = (const float*)d_in[0];
    const int*   ei    = (const int*)  d_in[1];
    const float* ea    = (const float*)d_in[2];
    const float* pmask = (const float*)d_in[3];
    const int*   batch = (const int*)  d_in[4];
    const float* We    = (const float*)d_in[5];
    const float* be    = (const float*)d_in[6];
    const float* W1    = (const float*)d_in[7];
    const float* b1    = (const float*)d_in[8];
    const float* W2    = (const float*)d_in[9];
    const float* b2    = (const float*)d_in[10];
    const float* epsp  = (const float*)d_in[11];
    const float* gamma = (const float*)d_in[12];
    const float* beta  = (const float*)d_in[13];
    const float* Wv    = (const float*)d_in[14];
    const float* bv    = (const float*)d_in[15];
    float* out = (float*)d_out;

    const int N = in_sizes[0] / D;     // 50000
    const int E = in_sizes[1] / 2;     // 600000
    const int* src = ei;
    const int* dst = ei + E;

    // Workspace: [deg | agg | psum | pcnt] (single memset), xres (aliased
    // below), pemb, scan scratch, xb (bf16 x), wb1t/wb2t.
    int*   deg  = (int*)d_ws;                           // N
    float* agg  = (float*)(deg + N);                    // N*D
    float* psum = agg + (size_t)N * D;                  // B*K*D
    float* pcnt = psum + (size_t)BGRAPH * K * D;        // B*K
    float* xres = pcnt + (size_t)BGRAPH * K;            // N*D
    float* pemb = xres + (size_t)N * D;                 // B*K*D
    float* extra = pemb + (size_t)BGRAPH * K * D;       // scan scratch (128)
    __hip_bfloat16* xb = (__hip_bfloat16*)(extra + 128);// N*D bf16
    short* wb1t = (short*)(xb + (size_t)N * D);         // D*D bf16
    short* wb2t = wb1t + (size_t)D * D;                 // D*D bf16

    // Aliased inside xres region (cursor 0.2MB + md 4.8MB + eab 19.2MB
    // = 24.2MB < 25.6MB); all consumed before mlp writes xres.
    int*   cursor = (int*)xres;                         // N
    uint2* md  = (uint2*)(((uintptr_t)(cursor + N) + 15) & ~(uintptr_t)15); // E
    short* eab = (short*)(md + E);                      // E*16 bf16

    int*  bsum  = (int*)extra;                          // 64
    int*  boffs = bsum + 64;                            // 64

    const int nb = (N + 1023) / 1024;                   // scan blocks (49)
    const int nchunks = (E + CH - 1) / CH;              // 9375
    const int NX = N * D, NEA = E * 16;
    const int NBX = NX / 2048;                          // 3125 (exact)
    const int NBE = (NEA / 8 + 255) / 256;              // 4688
    const int NBW = (2 * D * D) / 256;                  // 128
    const int NBH = (E / 4 + 255) / 256;                // 586

    const size_t zero_bytes =
        ((size_t)N + (size_t)N * D + (size_t)BGRAPH * K * D + BGRAPH * K) * sizeof(float);
    hipMemsetAsync(d_ws, 0, zero_bytes, stream);

    prep_kernel<<<NBX + NBE + NBW + NBH, 256, 0, stream>>>(
        x, ea, W1, W2, dst, xb, eab, wb1t, wb2t, deg, NX, NEA, E, NBX, NBE, NBW);
    scan_partial_kernel<<<nb, 256, 0, stream>>>(deg, bsum, N);
    scan_top_kernel<<<1, 64, 0, stream>>>(bsum, boffs, nb);
    scan_final_kernel<<<nb, 256, 0, stream>>>(deg, boffs, cursor, N);
    scatter_kernel<<<(E + 255) / 256, 256, 0, stream>>>(src, dst, cursor, md, E);
    gine_reduce_kernel<<<(nchunks + 3) / 4, 256, 0, stream>>>(
        xb, md, eab, We, be, agg, E);

    mlp_mfma_kernel<<<(N + MROWS - 1) / MROWS, 256, 0, stream>>>(
        x, agg, epsp, wb1t, b1, wb2t, b2, xres, N);
    pocket_sum_kernel<<<BGRAPH * PPARTS, 128, 0, stream>>>(
        xres, pmask, batch, psum, pcnt, N);
    pocket_emb_kernel<<<BGRAPH, 128, 0, stream>>>(psum, pcnt, Wv, bv, pemb);
    ln_kernel<<<(N + 3) / 4, 256, 0, stream>>>(
        xres, pmask, batch, pemb, gamma, beta, out, N);
}

// Round 3
// 359.349 us; speedup vs baseline: 1.0485x; 1.0485x over previous
//
#include <hip/hip_runtime.h>
#include <hip/hip_bf16.h>
#include <stdint.h>

#define D 128
#define K 8
#define BGRAPH 64
#define CH 64    // edges per wave in gine_reduce
#define GRP 4    // edges per inner group

typedef __attribute__((ext_vector_type(8))) short bf16x8;
typedef __attribute__((ext_vector_type(4))) float f32x4;
typedef __attribute__((ext_vector_type(2))) float f32x2;

__device__ __forceinline__ short f2bf(float f) {
    union { float f; uint32_t u; } v; v.f = f;
    const uint32_t r = (v.u + 0x7fffu + ((v.u >> 16) & 1u)) >> 16;
    return (short)r;
}
__device__ __forceinline__ float bflo(uint32_t u) {
    union { uint32_t u; float f; } v; v.u = u << 16; return v.f;
}
__device__ __forceinline__ float bfhi(uint32_t u) {
    union { uint32_t u; float f; } v; v.u = u & 0xffff0000u; return v.f;
}

// ---------------------------------------------------------------------------
// Stage 0 (fused prep): cast x->bf16, ea->bf16, W1/W2->bf16 transposed,
// We^T hi/lo bf16 (K padded to 32, bias row at k=16), dst in-degree hist.
// Disjoint blockIdx ranges.
// ---------------------------------------------------------------------------
__global__ __launch_bounds__(256) void prep_kernel(
    const float* __restrict__ x, const float* __restrict__ ea,
    const float* __restrict__ W1, const float* __restrict__ W2,
    const float* __restrict__ We, const float* __restrict__ be,
    const int* __restrict__ dst,
    __hip_bfloat16* __restrict__ xb, short* __restrict__ eab,
    short* __restrict__ wb1t, short* __restrict__ wb2t,
    short* __restrict__ webt,
    int* __restrict__ deg,
    int NX, int NEA, int E, int NBX, int NBE, int NBW)
{
    const int b = blockIdx.x;
    const int t = threadIdx.x;
    if (b < NBX) {
        // ---- cast x (8 floats/thread) ----
        const int i = b * 2048 + t * 8;
        if (i + 8 <= NX) {
            const float4 a = *(const float4*)(x + i);
            const float4 c = *(const float4*)(x + i + 4);
            short v[8];
            v[0] = f2bf(a.x); v[1] = f2bf(a.y); v[2] = f2bf(a.z); v[3] = f2bf(a.w);
            v[4] = f2bf(c.x); v[5] = f2bf(c.y); v[6] = f2bf(c.z); v[7] = f2bf(c.w);
            *(uint4*)((short*)xb + i) = *(const uint4*)v;
        }
    } else if (b < NBX + NBE) {
        // ---- cast ea (8 floats/thread) ----
        const int i = (b - NBX) * 2048 + t * 8;
        if (i + 8 <= NEA) {
            const float4 a = *(const float4*)(ea + i);
            const float4 c = *(const float4*)(ea + i + 4);
            short v[8];
            v[0] = f2bf(a.x); v[1] = f2bf(a.y); v[2] = f2bf(a.z); v[3] = f2bf(a.w);
            v[4] = f2bf(c.x); v[5] = f2bf(c.y); v[6] = f2bf(c.z); v[7] = f2bf(c.w);
            *(uint4*)(eab + i) = *(const uint4*)v;
        }
    } else if (b < NBX + NBE + NBW) {
        const int idx = (b - NBX - NBE) * 256 + t;
        if (idx < 2 * D * D) {
            // ---- W1/W2 transpose cast (1 elem/thread) ----
            const int which = idx >> 14;           // 0: W1, 1: W2
            const int rem = idx & 16383;
            const int n = rem >> 7;
            const int k = rem & 127;
            const float* W = which ? W2 : W1;
            short* O = which ? wb2t : wb1t;
            O[n * D + k] = f2bf(W[(size_t)k * D + n]);
        } else {
            // ---- webt[2][128][32]: We^T hi/lo bf16, bias row at k=16 ----
            const int widx = idx - 2 * D * D;      // 0..8191
            const int h = widx >> 12;              // 0 hi, 1 lo
            const int c = (widx >> 5) & 127;
            const int k = widx & 31;
            float val = 0.f;
            if (k < 16) val = We[k * D + c];
            else if (k == 16) val = be[c];
            const short hi = f2bf(val);
            short outv;
            if (h == 0) outv = hi;
            else {
                union { uint32_t u; float f; } fh;
                fh.u = ((uint32_t)(unsigned short)hi) << 16;
                outv = f2bf(val - fh.f);
            }
            webt[(h << 12) + c * 32 + k] = outv;
        }
    } else {
        // ---- dst histogram (4 edges/thread) ----
        const int i = ((b - NBX - NBE - NBW) * 256 + t) * 4;
        if (i + 4 <= E) {
            const int4 v = *(const int4*)(dst + i);
            atomicAdd(&deg[v.x], 1);
            atomicAdd(&deg[v.y], 1);
            atomicAdd(&deg[v.z], 1);
            atomicAdd(&deg[v.w], 1);
        } else {
            for (int j = i; j < E; ++j) atomicAdd(&deg[dst[j]], 1);
        }
    }
}

// ---------------------------------------------------------------------------
// Stage 1b: three-phase exclusive scan of deg[N] -> cursor[N]
// ---------------------------------------------------------------------------
__global__ __launch_bounds__(256) void scan_partial_kernel(
    const int* __restrict__ deg, int* __restrict__ bsum, int N)
{
    const int t = threadIdx.x;
    const int base = (blockIdx.x * 256 + t) * 4;
    int s = 0;
    if (base + 4 <= N) {
        const int4 v = *(const int4*)(deg + base);
        s = v.x + v.y + v.z + v.w;
    } else {
        for (int j = base; j < N; ++j) s += deg[j];
    }
    __shared__ int red[256];
    red[t] = s;
    __syncthreads();
    for (int off = 128; off; off >>= 1) {
        if (t < off) red[t] += red[t + off];
        __syncthreads();
    }
    if (t == 0) bsum[blockIdx.x] = red[0];
}

__global__ __launch_bounds__(64) void scan_top_kernel(
    const int* __restrict__ bsum, int* __restrict__ boffs, int nb)
{
    __shared__ int sh[64];
    const int t = threadIdx.x;
    const int v = (t < nb) ? bsum[t] : 0;
    sh[t] = v;
    __syncthreads();
    for (int off = 1; off < 64; off <<= 1) {
        const int u = (t >= off) ? sh[t - off] : 0;
        __syncthreads();
        sh[t] += u;
        __syncthreads();
    }
    if (t < nb) boffs[t] = sh[t] - v;      // exclusive
}

__global__ __launch_bounds__(256) void scan_final_kernel(
    const int* __restrict__ deg, const int* __restrict__ boffs,
    int* __restrict__ cursor, int N)
{
    const int t = threadIdx.x;
    const int base = (blockIdx.x * 256 + t) * 4;
    int v0 = 0, v1 = 0, v2 = 0, v3 = 0;
    if (base + 4 <= N) {
        const int4 v = *(const int4*)(deg + base);
        v0 = v.x; v1 = v.y; v2 = v.z; v3 = v.w;
    } else {
        if (base     < N) v0 = deg[base];
        if (base + 1 < N) v1 = deg[base + 1];
        if (base + 2 < N) v2 = deg[base + 2];
        if (base + 3 < N) v3 = deg[base + 3];
    }
    const int s = v0 + v1 + v2 + v3;
    __shared__ int sh[256];
    sh[t] = s;
    __syncthreads();
    for (int off = 1; off < 256; off <<= 1) {
        const int u = (t >= off) ? sh[t - off] : 0;
        __syncthreads();
        sh[t] += u;
        __syncthreads();
    }
    int ex = boffs[blockIdx.x] + sh[t] - s;
    if (base < N)     { cursor[base]     = ex; } ex += v0;
    if (base + 1 < N) { cursor[base + 1] = ex; } ex += v1;
    if (base + 2 < N) { cursor[base + 2] = ex; } ex += v2;
    if (base + 3 < N) { cursor[base + 3] = ex; }
}

// ---------------------------------------------------------------------------
// Stage 1c: scatter packed (src|dst<<16, eid) into dst-grouped order
// ---------------------------------------------------------------------------
__global__ __launch_bounds__(256) void scatter_kernel(
    const int* __restrict__ src, const int* __restrict__ dst,
    int* __restrict__ cursor, uint2* __restrict__ md, int E)
{
    const int i = blockIdx.x * 256 + threadIdx.x;
    if (i < E) {
        const unsigned sv = (unsigned)src[i];
        const unsigned dv = (unsigned)dst[i];
        const int p = atomicAdd(&cursor[dv], 1);
        md[p] = make_uint2(sv | (dv << 16), (unsigned)i);
    }
}

// ---------------------------------------------------------------------------
// Stage 1d: edge-parallel gather-reduce. The ea@We+be matvec now runs on the
// MFMA pipe: per 16-edge group, 16x16x32 bf16 MFMAs (A = eab rows, K padded
// to 32 with bias row 1.0 at k=16; B = We^T bf16 hi/lo split for ~f32 W
// precision) -> C fragments -> wave-private LDS tile. The serial dst-
// segmented loop then reads eemb rows from LDS (ds_read_b64) and does only
// x-add + relu + accumulate. md/x prefetch pipeline unchanged.
// ---------------------------------------------------------------------------
__device__ __forceinline__ void flush_row(
    float* __restrict__ agg, int node, int d, f32x2 acc, int first, int last)
{
    float* p = agg + (size_t)node * D + d;
    if (node == first || node == last) {
        if (acc.x != 0.f) atomicAdd(p,     acc.x);
        if (acc.y != 0.f) atomicAdd(p + 1, acc.y);
    } else {
        *(f32x2*)p = acc;
    }
}

__global__ __launch_bounds__(256) void gine_reduce_kernel(
    const __hip_bfloat16* __restrict__ xb, const uint2* __restrict__ md,
    const short* __restrict__ eab, const short* __restrict__ webt,
    float* __restrict__ agg, int E)
{
    __shared__ float lsh[4][16 * 132];   // 33.8 KB, wave-private tiles
    const int wave = threadIdx.x >> 6;
    const int lane = threadIdx.x & 63;
    const int chunk = __builtin_amdgcn_readfirstlane(blockIdx.x * 4 + wave);
    const int e0 = chunk * CH;
    if (e0 >= E) return;
    const int d = lane * 2;
    const int m = lane & 15;
    const int q = lane >> 4;
    float* myl = lsh[wave];
    const int NG = CH / GRP;                       // 16
    const unsigned* mdu = (const unsigned*)md;

    // B fragments: col = ct*16+m, k = q*8..q*8+7 (hi and lo tables)
    bf16x8 bH[8], bL[8];
    #pragma unroll
    for (int ct = 0; ct < 8; ++ct) {
        bH[ct] = *(const bf16x8*)(webt +        (ct * 16 + m) * 32 + q * 8);
        bL[ct] = *(const bf16x8*)(webt + 4096 + (ct * 16 + m) * 32 + q * 8);
    }

    // A fragment for mgroup 0: edge = e0 + m, k-half by q (q>=2 fixed at use)
    uint4 afcur = *(const uint4*)(eab +
        (size_t)mdu[2 * (e0 + m) + 1] * 16 + (q & 1) * 8);

    // scalar md pipeline + x prefetch (GRP granularity, as before)
    uint2 ma[GRP], mb[GRP], mc[GRP];
    #pragma unroll
    for (int j = 0; j < GRP; ++j) ma[j] = md[e0 + j];
    #pragma unroll
    for (int j = 0; j < GRP; ++j) mb[j] = md[e0 + GRP + j];
    #pragma unroll
    for (int j = 0; j < GRP; ++j) mc[j] = md[e0 + 2 * GRP + j];

    uint32_t xcur[GRP], xn1[GRP];
    #pragma unroll
    for (int j = 0; j < GRP; ++j)
        xcur[j] = *(const uint32_t*)(xb + (size_t)(ma[j].x & 0xffffu) * D + d);
    #pragma unroll
    for (int j = 0; j < GRP; ++j)
        xn1[j] = *(const uint32_t*)(xb + (size_t)(mb[j].x & 0xffffu) * D + d);

    const int first = (int)(ma[0].x >> 16);
    const int last  = (int)(md[e0 + CH - 1].x >> 16);

    f32x2 acc = {0.f, 0.f};
    int cur = first;

    for (int g = 0; g < NG; ++g) {
        if ((g & 3) == 0) {
            // ---- MFMA block for mgroup mg; prefetch A for mg+1 ----
            const int mg = g >> 2;
            uint4 afn = make_uint4(0u, 0u, 0u, 0u);
            if (mg < 3)
                afn = *(const uint4*)(eab +
                    (size_t)mdu[2 * (e0 + (mg + 1) * 16 + m) + 1] * 16 +
                    (q & 1) * 8);
            uint4 au = afcur;
            if (q >= 2)
                au = make_uint4(q == 2 ? 0x3f80u : 0u, 0u, 0u, 0u); // k16 = 1.0
            const bf16x8 a = *(const bf16x8*)&au;
            f32x4 mm[8];
            #pragma unroll
            for (int ct = 0; ct < 8; ++ct) {
                const f32x4 z = {0.f, 0.f, 0.f, 0.f};
                mm[ct] = __builtin_amdgcn_mfma_f32_16x16x32_bf16(a, bL[ct], z, 0, 0, 0);
            }
            #pragma unroll
            for (int ct = 0; ct < 8; ++ct)
                mm[ct] = __builtin_amdgcn_mfma_f32_16x16x32_bf16(a, bH[ct], mm[ct], 0, 0, 0);
            // C: edge row = q*4+r, col = ct*16+m  (stride 132: conflict-free)
            #pragma unroll
            for (int ct = 0; ct < 8; ++ct)
                #pragma unroll
                for (int r = 0; r < 4; ++r)
                    myl[(q * 4 + r) * 132 + ct * 16 + m] = mm[ct][r];
            afcur = afn;
        }

        // prefetch: meta g+3, x g+2
        uint2 mnew[GRP] = {};
        uint32_t xn2[GRP] = {};
        if (g + 3 < NG) {
            #pragma unroll
            for (int j = 0; j < GRP; ++j) mnew[j] = md[e0 + (g + 3) * GRP + j];
        }
        if (g + 2 < NG) {
            #pragma unroll
            for (int j = 0; j < GRP; ++j)
                xn2[j] = *(const uint32_t*)(xb + (size_t)(mc[j].x & 0xffffu) * D + d);
        }

        #pragma unroll
        for (int j = 0; j < GRP; ++j) {
            const int dk = (int)(ma[j].x >> 16);
            if (dk != cur) {                  // wave-uniform scalar branch
                flush_row(agg, cur, d, acc, first, last);
                acc.x = 0.f; acc.y = 0.f;
                cur = dk;
            }
            const uint32_t xu = xcur[j];
            const float2 em = *(const float2*)(myl + ((g & 3) * GRP + j) * 132 + d);
            const float m0 = em.x + bflo(xu);
            const float m1 = em.y + bfhi(xu);
            acc.x += m0 > 0.f ? m0 : 0.f;
            acc.y += m1 > 0.f ? m1 : 0.f;
        }

        #pragma unroll
        for (int j = 0; j < GRP; ++j) {
            ma[j] = mb[j]; mb[j] = mc[j]; mc[j] = mnew[j];
            xcur[j] = xn1[j]; xn1[j] = xn2[j];
        }
    }
    flush_row(agg, cur, d, acc, first, last);
}

// ---------------------------------------------------------------------------
// Stage 2: MFMA MLP.  x_res = relu(h@W1+b1)@W2+b2,  h = (1+eps)*x + agg.
// Block = 64 rows, 4 waves; wave owns 16 rows; t overwrites h in place.
// ---------------------------------------------------------------------------
#define MROWS 64
#define HSTR  132
__global__ __launch_bounds__(256) void mlp_mfma_kernel(
    const float* __restrict__ x, const float* __restrict__ agg,
    const float* __restrict__ epsp,
    const short* __restrict__ wb1t, const float* __restrict__ b1,
    const short* __restrict__ wb2t, const float* __restrict__ b2,
    float* __restrict__ xres, int N)
{
    __shared__ float hsh[MROWS * HSTR];   // 33.8 KB
    const int row0 = blockIdx.x * MROWS;
    const float ep = 1.0f + epsp[0];

    for (int i = threadIdx.x; i < MROWS * D / 4; i += 256) {
        const int flat = i * 4;
        const int r = flat >> 7;
        const int c = flat & (D - 1);
        const int row = row0 + r;
        float4 hv = make_float4(0.f, 0.f, 0.f, 0.f);
        if (row < N) {
            const float4 xv = *(const float4*)(x   + (size_t)row * D + c);
            const float4 av = *(const float4*)(agg + (size_t)row * D + c);
            hv = make_float4(ep * xv.x + av.x, ep * xv.y + av.y,
                             ep * xv.z + av.z, ep * xv.w + av.w);
        }
        *(float4*)(hsh + r * HSTR + c) = hv;
    }
    __syncthreads();

    const int lane = threadIdx.x & 63;
    const int wrow = (threadIdx.x >> 6) * 16;  // wave's 16-row window
    const int m = lane & 15;
    const int q = lane >> 4;

    f32x4 acc[8];

    // ---- layer 1 ----
    #pragma unroll
    for (int ct = 0; ct < 8; ++ct) {
        const float b = b1[ct * 16 + m];
        acc[ct] = (f32x4){b, b, b, b};
    }
    #pragma unroll
    for (int ks = 0; ks < 4; ++ks) {
        const float* ap = hsh + (wrow + m) * HSTR + ks * 32 + q * 8;
        float av[8];
        *(float4*)(av)     = *(const float4*)ap;
        *(float4*)(av + 4) = *(const float4*)(ap + 4);
        bf16x8 a;
        #pragma unroll
        for (int j = 0; j < 8; ++j) a[j] = f2bf(av[j]);
        #pragma unroll
        for (int ct = 0; ct < 8; ++ct) {
            const bf16x8 b = *(const bf16x8*)(wb1t + (ct * 16 + m) * D + ks * 32 + q * 8);
            acc[ct] = __builtin_amdgcn_mfma_f32_16x16x32_bf16(a, b, acc[ct], 0, 0, 0);
        }
    }
    #pragma unroll
    for (int ct = 0; ct < 8; ++ct)
        #pragma unroll
        for (int r = 0; r < 4; ++r) {
            const float v = acc[ct][r];
            hsh[(wrow + q * 4 + r) * HSTR + ct * 16 + m] = v > 0.f ? v : 0.f;
        }

    // ---- layer 2 ----
    #pragma unroll
    for (int ct = 0; ct < 8; ++ct) {
        const float b = b2[ct * 16 + m];
        acc[ct] = (f32x4){b, b, b, b};
    }
    #pragma unroll
    for (int ks = 0; ks < 4; ++ks) {
        const float* ap = hsh + (wrow + m) * HSTR + ks * 32 + q * 8;
        float av[8];
        *(float4*)(av)     = *(const float4*)ap;
        *(float4*)(av + 4) = *(const float4*)(ap + 4);
        bf16x8 a;
        #pragma unroll
        for (int j = 0; j < 8; ++j) a[j] = f2bf(av[j]);
        #pragma unroll
        for (int ct = 0; ct < 8; ++ct) {
            const bf16x8 b = *(const bf16x8*)(wb2t + (ct * 16 + m) * D + ks * 32 + q * 8);
            acc[ct] = __builtin_amdgcn_mfma_f32_16x16x32_bf16(a, b, acc[ct], 0, 0, 0);
        }
    }
    #pragma unroll
    for (int r = 0; r < 4; ++r) {
        const int row = row0 + wrow + q * 4 + r;
        if (row < N) {
            #pragma unroll
            for (int ct = 0; ct < 8; ++ct)
                xres[(size_t)row * D + ct * 16 + m] = acc[ct][r];
        }
    }
}

// ---------------------------------------------------------------------------
// Stage 3: per-(graph,pocket) masked sums
// ---------------------------------------------------------------------------
#define PPARTS 32
__global__ __launch_bounds__(128) void pocket_sum_kernel(
    const float* __restrict__ xres, const float* __restrict__ pmask,
    const int* __restrict__ batch,
    float* __restrict__ psum, float* __restrict__ pcnt, int N)
{
    const int g = blockIdx.x / PPARTS;
    const int part = blockIdx.x % PPARTS;

    int lo, hi;
    {
        int l = 0, r = N;
        while (l < r) { int m = (l + r) >> 1; if (batch[m] < g) l = m + 1; else r = m; }
        lo = l;
        r = N;
        while (l < r) { int m = (l + r) >> 1; if (batch[m] < g + 1) l = m + 1; else r = m; }
        hi = l;
    }
    const int cnt = hi - lo;
    const int per = (cnt + PPARTS - 1) / PPARTS;
    const int s = lo + part * per;
    const int e = min(s + per, hi);

    const int d = threadIdx.x;
    float acc[K];
    #pragma unroll
    for (int k = 0; k < K; ++k) acc[k] = 0.0f;
    float c = 0.0f;

    for (int n = s; n < e; ++n) {
        const float xv = xres[(size_t)n * D + d];
        const float4 m0 = *(const float4*)(pmask + (size_t)n * K);
        const float4 m1 = *(const float4*)(pmask + (size_t)n * K + 4);
        acc[0] += m0.x * xv; acc[1] += m0.y * xv;
        acc[2] += m0.z * xv; acc[3] += m0.w * xv;
        acc[4] += m1.x * xv; acc[5] += m1.y * xv;
        acc[6] += m1.z * xv; acc[7] += m1.w * xv;
        if (d < K) c += pmask[(size_t)n * K + d];
    }
    #pragma unroll
    for (int k = 0; k < K; ++k)
        atomicAdd(&psum[(size_t)g * (K * D) + k * D + d], acc[k]);
    if (d < K) atomicAdd(&pcnt[g * K + d], c);
}

// ---------------------------------------------------------------------------
// Stage 4: pocket_emb = (psum / (pcnt + 1e-9)) @ Wv + bv
// ---------------------------------------------------------------------------
__global__ __launch_bounds__(128) void pocket_emb_kernel(
    const float* __restrict__ psum, const float* __restrict__ pcnt,
    const float* __restrict__ Wv, const float* __restrict__ bv,
    float* __restrict__ pemb)
{
    __shared__ float smean[K * D];
    __shared__ float scnt[K];
    const int g = blockIdx.x;
    const int d = threadIdx.x;
    if (d < K) scnt[d] = pcnt[g * K + d];
    __syncthreads();
    #pragma unroll
    for (int k = 0; k < K; ++k)
        smean[k * D + d] = psum[(size_t)g * (K * D) + k * D + d] / (scnt[k] + 1e-9f);
    __syncthreads();

    float acc[K];
    const float bvv = bv[d];
    #pragma unroll
    for (int k = 0; k < K; ++k) acc[k] = bvv;
    for (int j = 0; j < D; ++j) {
        const float w = Wv[j * D + d];
        #pragma unroll
        for (int k = 0; k < K; ++k) acc[k] += smean[k * D + j] * w;
    }
    #pragma unroll
    for (int k = 0; k < K; ++k)
        pemb[(size_t)g * (K * D) + k * D + d] = acc[k];
}

// ---------------------------------------------------------------------------
// Stage 5: feedback gather + LayerNorm + ReLU. One wave per node.
// ---------------------------------------------------------------------------
__global__ __launch_bounds__(256) void ln_kernel(
    const float* __restrict__ xres, const float* __restrict__ pmask,
    const int* __restrict__ batch, const float* __restrict__ pemb,
    const float* __restrict__ gamma, const float* __restrict__ beta,
    float* __restrict__ out, int N)
{
    const int wave = threadIdx.x >> 6;
    const int lane = threadIdx.x & 63;
    const int n = blockIdx.x * 4 + wave;
    if (n >= N) return;
    const int d = lane * 2;

    float2 v = *(const float2*)(xres + (size_t)n * D + d);
    const int g = batch[n];
    const float* pe = pemb + (size_t)g * (K * D);
    const float4 m0 = *(const float4*)(pmask + (size_t)n * K);
    const float4 m1 = *(const float4*)(pmask + (size_t)n * K + 4);
    const float mk[K] = {m0.x, m0.y, m0.z, m0.w, m1.x, m1.y, m1.z, m1.w};
    #pragma unroll
    for (int k = 0; k < K; ++k) {
        if (mk[k] != 0.0f) {   // wave-uniform branch
            const float2 p = *(const float2*)(pe + k * D + d);
            v.x += mk[k] * p.x;
            v.y += mk[k] * p.y;
        }
    }

    float s = v.x + v.y;
    #pragma unroll
    for (int off = 32; off; off >>= 1) s += __shfl_xor(s, off, 64);
    const float mu = s * (1.0f / 128.0f);
    const float d0 = v.x - mu, d1 = v.y - mu;
    float sq = d0 * d0 + d1 * d1;
    #pragma unroll
    for (int off = 32; off; off >>= 1) sq += __shfl_xor(sq, off, 64);
    const float var = sq * (1.0f / 128.0f);
    const float inv = rsqrtf(var + 1e-5f);

    const float2 gm = *(const float2*)(gamma + d);
    const float2 bt = *(const float2*)(beta + d);
    float y0 = d0 * inv * gm.x + bt.x;
    float y1 = d1 * inv * gm.y + bt.y;
    y0 = y0 > 0.0f ? y0 : 0.0f;
    y1 = y1 > 0.0f ? y1 : 0.0f;
    *(float2*)(out + (size_t)n * D + d) = make_float2(y0, y1);
}

// ---------------------------------------------------------------------------
extern "C" void kernel_launch(void* const* d_in, const int* in_sizes, int n_in,
                              void* d_out, int out_size, void* d_ws, size_t ws_size,
                              hipStream_t stream)
{
    const float* x     = (const float*)d_in[0];
    const int*   ei    = (const int*)  d_in[1];
    const float* ea    = (const float*)d_in[2];
    const float* pmask = (const float*)d_in[3];
    const int*   batch = (const int*)  d_in[4];
    const float* We    = (const float*)d_in[5];
    const float* be    = (const float*)d_in[6];
    const float* W1    = (const float*)d_in[7];
    const float* b1    = (const float*)d_in[8];
    const float* W2    = (const float*)d_in[9];
    const float* b2    = (const float*)d_in[10];
    const float* epsp  = (const float*)d_in[11];
    const float* gamma = (const float*)d_in[12];
    const float* beta  = (const float*)d_in[13];
    const float* Wv    = (const float*)d_in[14];
    const float* bv    = (const float*)d_in[15];
    float* out = (float*)d_out;

    const int N = in_sizes[0] / D;     // 50000
    const int E = in_sizes[1] / 2;     // 600000
    const int* src = ei;
    const int* dst = ei + E;

    // Workspace: [deg | agg | psum | pcnt] (single memset), xres (aliased
    // below), pemb, scan scratch, xb (bf16 x), wb1t/wb2t/webt.
    int*   deg  = (int*)d_ws;                           // N
    float* agg  = (float*)(deg + N);                    // N*D
    float* psum = agg + (size_t)N * D;                  // B*K*D
    float* pcnt = psum + (size_t)BGRAPH * K * D;        // B*K
    float* xres = pcnt + (size_t)BGRAPH * K;            // N*D
    float* pemb = xres + (size_t)N * D;                 // B*K*D
    float* extra = pemb + (size_t)BGRAPH * K * D;       // scan scratch (128)
    __hip_bfloat16* xb = (__hip_bfloat16*)(extra + 128);// N*D bf16
    short* wb1t = (short*)(xb + (size_t)N * D);         // D*D bf16
    short* wb2t = wb1t + (size_t)D * D;                 // D*D bf16
    short* webt = wb2t + (size_t)D * D;                 // 2*128*32 bf16 (8K shorts)

    // Aliased inside xres region (cursor 0.2MB + md 4.8MB + eab 19.2MB
    // = 24.2MB < 25.6MB); all consumed before mlp writes xres.
    int*   cursor = (int*)xres;                         // N
    uint2* md  = (uint2*)(((uintptr_t)(cursor + N) + 15) & ~(uintptr_t)15); // E
    short* eab = (short*)(md + E);                      // E*16 bf16

    int*  bsum  = (int*)extra;                          // 64
    int*  boffs = bsum + 64;                            // 64

    const int nb = (N + 1023) / 1024;                   // scan blocks (49)
    const int nchunks = (E + CH - 1) / CH;              // 9375
    const int NX = N * D, NEA = E * 16;
    const int NBX = NX / 2048;                          // 3125 (exact)
    const int NBE = (NEA / 8 + 255) / 256;              // 4688
    const int NBW = (2 * D * D + 2 * 128 * 32) / 256;   // 160 (exact)
    const int NBH = (E / 4 + 255) / 256;                // 586

    const size_t zero_bytes =
        ((size_t)N + (size_t)N * D + (size_t)BGRAPH * K * D + BGRAPH * K) * sizeof(float);
    hipMemsetAsync(d_ws, 0, zero_bytes, stream);

    prep_kernel<<<NBX + NBE + NBW + NBH, 256, 0, stream>>>(
        x, ea, W1, W2, We, be, dst, xb, eab, wb1t, wb2t, webt, deg,
        NX, NEA, E, NBX, NBE, NBW);
    scan_partial_kernel<<<nb, 256, 0, stream>>>(deg, bsum, N);
    scan_top_kernel<<<1, 64, 0, stream>>>(bsum, boffs, nb);
    scan_final_kernel<<<nb, 256, 0, stream>>>(deg, boffs, cursor, N);
    scatter_kernel<<<(E + 255) / 256, 256, 0, stream>>>(src, dst, cursor, md, E);
    gine_reduce_kernel<<<(nchunks + 3) / 4, 256, 0, stream>>>(
        xb, md, eab, webt, agg, E);

    mlp_mfma_kernel<<<(N + MROWS - 1) / MROWS, 256, 0, stream>>>(
        x, agg, epsp, wb1t, b1, wb2t, b2, xres, N);
    pocket_sum_kernel<<<BGRAPH * PPARTS, 128, 0, stream>>>(
        xres, pmask, batch, psum, pcnt, N);
    pocket_emb_kernel<<<BGRAPH, 128, 0, stream>>>(psum, pcnt, Wv, bv, pemb);
    ln_kernel<<<(N + 3) / 4, 256, 0, stream>>>(
        xres, pmask, batch, pemb, gamma, beta, out, N);
}

// Round 4
// 358.548 us; speedup vs baseline: 1.0508x; 1.0022x over previous
//
#include <hip/hip_runtime.h>
#include <hip/hip_bf16.h>
#include <stdint.h>

#define D 128
#define K 8
#define BGRAPH 64
#define CH 64    // edges per wave in gine_reduce
#define GRP 4    // edges per inner group

typedef __attribute__((ext_vector_type(8))) short bf16x8;
typedef __attribute__((ext_vector_type(4))) float f32x4;
typedef __attribute__((ext_vector_type(2))) float f32x2;

__device__ __forceinline__ short f2bf(float f) {
    union { float f; uint32_t u; } v; v.f = f;
    const uint32_t r = (v.u + 0x7fffu + ((v.u >> 16) & 1u)) >> 16;
    return (short)r;
}
__device__ __forceinline__ float bflo(uint32_t u) {
    union { uint32_t u; float f; } v; v.u = u << 16; return v.f;
}
__device__ __forceinline__ float bfhi(uint32_t u) {
    union { uint32_t u; float f; } v; v.u = u & 0xffff0000u; return v.f;
}

// ---------------------------------------------------------------------------
// Stage 0 (fused prep): cast x->bf16, W1/W2->bf16 transposed, We^T hi/lo bf16
// (K padded to 32, bias row at k=16), dst in-degree hist. (ea is consumed
// directly as f32 by gine_reduce now — no bf16 materialization pass.)
// ---------------------------------------------------------------------------
__global__ __launch_bounds__(256) void prep_kernel(
    const float* __restrict__ x,
    const float* __restrict__ W1, const float* __restrict__ W2,
    const float* __restrict__ We, const float* __restrict__ be,
    const int* __restrict__ dst,
    __hip_bfloat16* __restrict__ xb,
    short* __restrict__ wb1t, short* __restrict__ wb2t,
    short* __restrict__ webt,
    int* __restrict__ deg,
    int NX, int E, int NBX, int NBW)
{
    const int b = blockIdx.x;
    const int t = threadIdx.x;
    if (b < NBX) {
        // ---- cast x (8 floats/thread) ----
        const int i = b * 2048 + t * 8;
        if (i + 8 <= NX) {
            const float4 a = *(const float4*)(x + i);
            const float4 c = *(const float4*)(x + i + 4);
            short v[8];
            v[0] = f2bf(a.x); v[1] = f2bf(a.y); v[2] = f2bf(a.z); v[3] = f2bf(a.w);
            v[4] = f2bf(c.x); v[5] = f2bf(c.y); v[6] = f2bf(c.z); v[7] = f2bf(c.w);
            *(uint4*)((short*)xb + i) = *(const uint4*)v;
        }
    } else if (b < NBX + NBW) {
        const int idx = (b - NBX) * 256 + t;
        if (idx < 2 * D * D) {
            // ---- W1/W2 transpose cast (1 elem/thread) ----
            const int which = idx >> 14;           // 0: W1, 1: W2
            const int rem = idx & 16383;
            const int n = rem >> 7;
            const int k = rem & 127;
            const float* W = which ? W2 : W1;
            short* O = which ? wb2t : wb1t;
            O[n * D + k] = f2bf(W[(size_t)k * D + n]);
        } else {
            // ---- webt[2][128][32]: We^T hi/lo bf16, bias row at k=16 ----
            const int widx = idx - 2 * D * D;      // 0..8191
            const int h = widx >> 12;              // 0 hi, 1 lo
            const int c = (widx >> 5) & 127;
            const int k = widx & 31;
            float val = 0.f;
            if (k < 16) val = We[k * D + c];
            else if (k == 16) val = be[c];
            const short hi = f2bf(val);
            short outv;
            if (h == 0) outv = hi;
            else {
                union { uint32_t u; float f; } fh;
                fh.u = ((uint32_t)(unsigned short)hi) << 16;
                outv = f2bf(val - fh.f);
            }
            webt[(h << 12) + c * 32 + k] = outv;
        }
    } else {
        // ---- dst histogram (4 edges/thread) ----
        const int i = ((b - NBX - NBW) * 256 + t) * 4;
        if (i + 4 <= E) {
            const int4 v = *(const int4*)(dst + i);
            atomicAdd(&deg[v.x], 1);
            atomicAdd(&deg[v.y], 1);
            atomicAdd(&deg[v.z], 1);
            atomicAdd(&deg[v.w], 1);
        } else {
            for (int j = i; j < E; ++j) atomicAdd(&deg[dst[j]], 1);
        }
    }
}

// ---------------------------------------------------------------------------
// Stage 1b: three-phase exclusive scan of deg[N] -> cursor[N]
// ---------------------------------------------------------------------------
__global__ __launch_bounds__(256) void scan_partial_kernel(
    const int* __restrict__ deg, int* __restrict__ bsum, int N)
{
    const int t = threadIdx.x;
    const int base = (blockIdx.x * 256 + t) * 4;
    int s = 0;
    if (base + 4 <= N) {
        const int4 v = *(const int4*)(deg + base);
        s = v.x + v.y + v.z + v.w;
    } else {
        for (int j = base; j < N; ++j) s += deg[j];
    }
    __shared__ int red[256];
    red[t] = s;
    __syncthreads();
    for (int off = 128; off; off >>= 1) {
        if (t < off) red[t] += red[t + off];
        __syncthreads();
    }
    if (t == 0) bsum[blockIdx.x] = red[0];
}

__global__ __launch_bounds__(64) void scan_top_kernel(
    const int* __restrict__ bsum, int* __restrict__ boffs, int nb)
{
    __shared__ int sh[64];
    const int t = threadIdx.x;
    const int v = (t < nb) ? bsum[t] : 0;
    sh[t] = v;
    __syncthreads();
    for (int off = 1; off < 64; off <<= 1) {
        const int u = (t >= off) ? sh[t - off] : 0;
        __syncthreads();
        sh[t] += u;
        __syncthreads();
    }
    if (t < nb) boffs[t] = sh[t] - v;      // exclusive
}

__global__ __launch_bounds__(256) void scan_final_kernel(
    const int* __restrict__ deg, const int* __restrict__ boffs,
    int* __restrict__ cursor, int N)
{
    const int t = threadIdx.x;
    const int base = (blockIdx.x * 256 + t) * 4;
    int v0 = 0, v1 = 0, v2 = 0, v3 = 0;
    if (base + 4 <= N) {
        const int4 v = *(const int4*)(deg + base);
        v0 = v.x; v1 = v.y; v2 = v.z; v3 = v.w;
    } else {
        if (base     < N) v0 = deg[base];
        if (base + 1 < N) v1 = deg[base + 1];
        if (base + 2 < N) v2 = deg[base + 2];
        if (base + 3 < N) v3 = deg[base + 3];
    }
    const int s = v0 + v1 + v2 + v3;
    __shared__ int sh[256];
    sh[t] = s;
    __syncthreads();
    for (int off = 1; off < 256; off <<= 1) {
        const int u = (t >= off) ? sh[t - off] : 0;
        __syncthreads();
        sh[t] += u;
        __syncthreads();
    }
    int ex = boffs[blockIdx.x] + sh[t] - s;
    if (base < N)     { cursor[base]     = ex; } ex += v0;
    if (base + 1 < N) { cursor[base + 1] = ex; } ex += v1;
    if (base + 2 < N) { cursor[base + 2] = ex; } ex += v2;
    if (base + 3 < N) { cursor[base + 3] = ex; }
}

// ---------------------------------------------------------------------------
// Stage 1c: scatter packed (src|dst<<16, eid) into dst-grouped order
// ---------------------------------------------------------------------------
__global__ __launch_bounds__(256) void scatter_kernel(
    const int* __restrict__ src, const int* __restrict__ dst,
    int* __restrict__ cursor, uint2* __restrict__ md, int E)
{
    const int i = blockIdx.x * 256 + threadIdx.x;
    if (i < E) {
        const unsigned sv = (unsigned)src[i];
        const unsigned dv = (unsigned)dst[i];
        const int p = atomicAdd(&cursor[dv], 1);
        md[p] = make_uint2(sv | (dv << 16), (unsigned)i);
    }
}

// ---------------------------------------------------------------------------
// Stage 1d: edge-parallel gather-reduce. ea@We+be on the MFMA pipe (A = ea
// rows gathered as f32, cvt in-register; K padded to 32 with bias row at
// k=16; B = We^T bf16 hi/lo) -> XOR-swizzled 16x128 LDS tile (32KB/block ->
// 5 blocks/CU). Serial dst-segmented consume reads eemb from LDS. Pipeline:
// md 4 groups ahead, x 3 ahead, ea 1 mgroup ahead.
// ---------------------------------------------------------------------------
__device__ __forceinline__ void flush_row(
    float* __restrict__ agg, int node, int d, f32x2 acc, int first, int last)
{
    float* p = agg + (size_t)node * D + d;
    if (node == first || node == last) {
        if (acc.x != 0.f) atomicAdd(p,     acc.x);
        if (acc.y != 0.f) atomicAdd(p + 1, acc.y);
    } else {
        *(f32x2*)p = acc;
    }
}

__global__ __launch_bounds__(256) void gine_reduce_kernel(
    const __hip_bfloat16* __restrict__ xb, const uint2* __restrict__ md,
    const float* __restrict__ ea, const short* __restrict__ webt,
    float* __restrict__ agg, int E)
{
    __shared__ float lsh[4][16 * 128];   // 32 KB total, wave-private tiles
    const int wave = threadIdx.x >> 6;
    const int lane = threadIdx.x & 63;
    const int chunk = __builtin_amdgcn_readfirstlane(blockIdx.x * 4 + wave);
    const int e0 = chunk * CH;
    if (e0 >= E) return;
    const int d = lane * 2;
    const int m = lane & 15;
    const int q = lane >> 4;
    float* myl = lsh[wave];
    const int NG = CH / GRP;                       // 16
    const unsigned* mdu = (const unsigned*)md;
    const int qswz = (q & 1) << 4;                 // LDS write-col xor

    // B fragments: col = ct*16+m, k = q*8..q*8+7 (hi and lo tables)
    bf16x8 bH[8], bL[8];
    #pragma unroll
    for (int ct = 0; ct < 8; ++ct) {
        bH[ct] = *(const bf16x8*)(webt +        (ct * 16 + m) * 32 + q * 8);
        bL[ct] = *(const bf16x8*)(webt + 4096 + (ct * 16 + m) * 32 + q * 8);
    }

    // A prefetch for mgroup 0: edge = e0 + m, 8 f32 at k-half (q&1); only
    // lanes q<2 carry real A data (q>=2 is bias/zero pad).
    float4 af0 = {0.f, 0.f, 0.f, 0.f}, af1 = {0.f, 0.f, 0.f, 0.f};
    if ((q & 2) == 0) {
        const float* p = ea + (size_t)mdu[2 * (e0 + m) + 1] * 16 + (q & 1) * 8;
        af0 = *(const float4*)p;
        af1 = *(const float4*)(p + 4);
    }

    // scalar md pipeline (4 deep) + x prefetch (3 deep)
    uint2 m0[GRP], m1g[GRP], m2g[GRP], m3g[GRP];
    #pragma unroll
    for (int j = 0; j < GRP; ++j) m0[j]  = md[e0 + j];
    #pragma unroll
    for (int j = 0; j < GRP; ++j) m1g[j] = md[e0 + GRP + j];
    #pragma unroll
    for (int j = 0; j < GRP; ++j) m2g[j] = md[e0 + 2 * GRP + j];
    #pragma unroll
    for (int j = 0; j < GRP; ++j) m3g[j] = md[e0 + 3 * GRP + j];

    uint32_t x0[GRP], x1[GRP], x2[GRP];
    #pragma unroll
    for (int j = 0; j < GRP; ++j)
        x0[j] = *(const uint32_t*)(xb + (size_t)(m0[j].x  & 0xffffu) * D + d);
    #pragma unroll
    for (int j = 0; j < GRP; ++j)
        x1[j] = *(const uint32_t*)(xb + (size_t)(m1g[j].x & 0xffffu) * D + d);
    #pragma unroll
    for (int j = 0; j < GRP; ++j)
        x2[j] = *(const uint32_t*)(xb + (size_t)(m2g[j].x & 0xffffu) * D + d);

    const int first = (int)(m0[0].x >> 16);
    const int last  = (int)(md[e0 + CH - 1].x >> 16);

    f32x2 acc = {0.f, 0.f};
    int cur = first;

    for (int g = 0; g < NG; ++g) {
        if ((g & 3) == 0) {
            // ---- MFMA block for mgroup mg; prefetch ea for mg+1 ----
            const int mg = g >> 2;
            float4 an0 = {0.f, 0.f, 0.f, 0.f}, an1 = {0.f, 0.f, 0.f, 0.f};
            if (mg < 3 && (q & 2) == 0) {
                const float* p = ea +
                    (size_t)mdu[2 * (e0 + (mg + 1) * 16 + m) + 1] * 16 +
                    (q & 1) * 8;
                an0 = *(const float4*)p;
                an1 = *(const float4*)(p + 4);
            }
            bf16x8 a;
            if (q < 2) {
                a[0] = f2bf(af0.x); a[1] = f2bf(af0.y);
                a[2] = f2bf(af0.z); a[3] = f2bf(af0.w);
                a[4] = f2bf(af1.x); a[5] = f2bf(af1.y);
                a[6] = f2bf(af1.z); a[7] = f2bf(af1.w);
            } else {
                a = (bf16x8){(short)(q == 2 ? 0x3f80 : 0), 0, 0, 0, 0, 0, 0, 0};
            }
            f32x4 mm[8];
            #pragma unroll
            for (int ct = 0; ct < 8; ++ct) {
                const f32x4 z = {0.f, 0.f, 0.f, 0.f};
                mm[ct] = __builtin_amdgcn_mfma_f32_16x16x32_bf16(a, bL[ct], z, 0, 0, 0);
            }
            #pragma unroll
            for (int ct = 0; ct < 8; ++ct)
                mm[ct] = __builtin_amdgcn_mfma_f32_16x16x32_bf16(a, bH[ct], mm[ct], 0, 0, 0);
            // C: edge row = q*4+r, col = (ct*16+m) ^ qswz  (2-way banks, free)
            #pragma unroll
            for (int ct = 0; ct < 8; ++ct)
                #pragma unroll
                for (int r = 0; r < 4; ++r)
                    myl[(q * 4 + r) * 128 + ((ct * 16 + m) ^ qswz)] = mm[ct][r];
            af0 = an0; af1 = an1;
        }

        // prefetch: meta g+4, x g+3 (via m3g)
        uint2 mnew[GRP] = {};
        uint32_t xn[GRP] = {};
        if (g + 4 < NG) {
            #pragma unroll
            for (int j = 0; j < GRP; ++j) mnew[j] = md[e0 + (g + 4) * GRP + j];
        }
        if (g + 3 < NG) {
            #pragma unroll
            for (int j = 0; j < GRP; ++j)
                xn[j] = *(const uint32_t*)(xb + (size_t)(m3g[j].x & 0xffffu) * D + d);
        }

        #pragma unroll
        for (int j = 0; j < GRP; ++j) {
            const int dk = (int)(m0[j].x >> 16);
            if (dk != cur) {                  // wave-uniform scalar branch
                flush_row(agg, cur, d, acc, first, last);
                acc.x = 0.f; acc.y = 0.f;
                cur = dk;
            }
            const uint32_t xu = x0[j];
            const int el = (g & 3) * GRP + j;
            const float2 em = *(const float2*)(myl + el * 128 +
                                               (d ^ ((el & 4) << 2)));
            const float v0 = em.x + bflo(xu);
            const float v1 = em.y + bfhi(xu);
            acc.x += v0 > 0.f ? v0 : 0.f;
            acc.y += v1 > 0.f ? v1 : 0.f;
        }

        #pragma unroll
        for (int j = 0; j < GRP; ++j) {
            m0[j] = m1g[j]; m1g[j] = m2g[j]; m2g[j] = m3g[j]; m3g[j] = mnew[j];
            x0[j] = x1[j]; x1[j] = x2[j]; x2[j] = xn[j];
        }
    }
    flush_row(agg, cur, d, acc, first, last);
}

// ---------------------------------------------------------------------------
// Stage 2: MFMA MLP.  x_res = relu(h@W1+b1)@W2+b2,  h = (1+eps)*x + agg.
// Block = 64 rows, 4 waves; wave owns 16 rows; t overwrites h in place.
// ---------------------------------------------------------------------------
#define MROWS 64
#define HSTR  132
__global__ __launch_bounds__(256) void mlp_mfma_kernel(
    const float* __restrict__ x, const float* __restrict__ agg,
    const float* __restrict__ epsp,
    const short* __restrict__ wb1t, const float* __restrict__ b1,
    const short* __restrict__ wb2t, const float* __restrict__ b2,
    float* __restrict__ xres, int N)
{
    __shared__ float hsh[MROWS * HSTR];   // 33.8 KB
    const int row0 = blockIdx.x * MROWS;
    const float ep = 1.0f + epsp[0];

    for (int i = threadIdx.x; i < MROWS * D / 4; i += 256) {
        const int flat = i * 4;
        const int r = flat >> 7;
        const int c = flat & (D - 1);
        const int row = row0 + r;
        float4 hv = make_float4(0.f, 0.f, 0.f, 0.f);
        if (row < N) {
            const float4 xv = *(const float4*)(x   + (size_t)row * D + c);
            const float4 av = *(const float4*)(agg + (size_t)row * D + c);
            hv = make_float4(ep * xv.x + av.x, ep * xv.y + av.y,
                             ep * xv.z + av.z, ep * xv.w + av.w);
        }
        *(float4*)(hsh + r * HSTR + c) = hv;
    }
    __syncthreads();

    const int lane = threadIdx.x & 63;
    const int wrow = (threadIdx.x >> 6) * 16;  // wave's 16-row window
    const int m = lane & 15;
    const int q = lane >> 4;

    f32x4 acc[8];

    // ---- layer 1 ----
    #pragma unroll
    for (int ct = 0; ct < 8; ++ct) {
        const float b = b1[ct * 16 + m];
        acc[ct] = (f32x4){b, b, b, b};
    }
    #pragma unroll
    for (int ks = 0; ks < 4; ++ks) {
        const float* ap = hsh + (wrow + m) * HSTR + ks * 32 + q * 8;
        float av[8];
        *(float4*)(av)     = *(const float4*)ap;
        *(float4*)(av + 4) = *(const float4*)(ap + 4);
        bf16x8 a;
        #pragma unroll
        for (int j = 0; j < 8; ++j) a[j] = f2bf(av[j]);
        #pragma unroll
        for (int ct = 0; ct < 8; ++ct) {
            const bf16x8 b = *(const bf16x8*)(wb1t + (ct * 16 + m) * D + ks * 32 + q * 8);
            acc[ct] = __builtin_amdgcn_mfma_f32_16x16x32_bf16(a, b, acc[ct], 0, 0, 0);
        }
    }
    #pragma unroll
    for (int ct = 0; ct < 8; ++ct)
        #pragma unroll
        for (int r = 0; r < 4; ++r) {
            const float v = acc[ct][r];
            hsh[(wrow + q * 4 + r) * HSTR + ct * 16 + m] = v > 0.f ? v : 0.f;
        }

    // ---- layer 2 ----
    #pragma unroll
    for (int ct = 0; ct < 8; ++ct) {
        const float b = b2[ct * 16 + m];
        acc[ct] = (f32x4){b, b, b, b};
    }
    #pragma unroll
    for (int ks = 0; ks < 4; ++ks) {
        const float* ap = hsh + (wrow + m) * HSTR + ks * 32 + q * 8;
        float av[8];
        *(float4*)(av)     = *(const float4*)ap;
        *(float4*)(av + 4) = *(const float4*)(ap + 4);
        bf16x8 a;
        #pragma unroll
        for (int j = 0; j < 8; ++j) a[j] = f2bf(av[j]);
        #pragma unroll
        for (int ct = 0; ct < 8; ++ct) {
            const bf16x8 b = *(const bf16x8*)(wb2t + (ct * 16 + m) * D + ks * 32 + q * 8);
            acc[ct] = __builtin_amdgcn_mfma_f32_16x16x32_bf16(a, b, acc[ct], 0, 0, 0);
        }
    }
    #pragma unroll
    for (int r = 0; r < 4; ++r) {
        const int row = row0 + wrow + q * 4 + r;
        if (row < N) {
            #pragma unroll
            for (int ct = 0; ct < 8; ++ct)
                xres[(size_t)row * D + ct * 16 + m] = acc[ct][r];
        }
    }
}

// ---------------------------------------------------------------------------
// Stage 3: per-(graph,pocket) masked sums
// ---------------------------------------------------------------------------
#define PPARTS 32
__global__ __launch_bounds__(128) void pocket_sum_kernel(
    const float* __restrict__ xres, const float* __restrict__ pmask,
    const int* __restrict__ batch,
    float* __restrict__ psum, float* __restrict__ pcnt, int N)
{
    const int g = blockIdx.x / PPARTS;
    const int part = blockIdx.x % PPARTS;

    int lo, hi;
    {
        int l = 0, r = N;
        while (l < r) { int m = (l + r) >> 1; if (batch[m] < g) l = m + 1; else r = m; }
        lo = l;
        r = N;
        while (l < r) { int m = (l + r) >> 1; if (batch[m] < g + 1) l = m + 1; else r = m; }
        hi = l;
    }
    const int cnt = hi - lo;
    const int per = (cnt + PPARTS - 1) / PPARTS;
    const int s = lo + part * per;
    const int e = min(s + per, hi);

    const int d = threadIdx.x;
    float acc[K];
    #pragma unroll
    for (int k = 0; k < K; ++k) acc[k] = 0.0f;
    float c = 0.0f;

    for (int n = s; n < e; ++n) {
        const float xv = xres[(size_t)n * D + d];
        const float4 m0 = *(const float4*)(pmask + (size_t)n * K);
        const float4 m1 = *(const float4*)(pmask + (size_t)n * K + 4);
        acc[0] += m0.x * xv; acc[1] += m0.y * xv;
        acc[2] += m0.z * xv; acc[3] += m0.w * xv;
        acc[4] += m1.x * xv; acc[5] += m1.y * xv;
        acc[6] += m1.z * xv; acc[7] += m1.w * xv;
        if (d < K) c += pmask[(size_t)n * K + d];
    }
    #pragma unroll
    for (int k = 0; k < K; ++k)
        atomicAdd(&psum[(size_t)g * (K * D) + k * D + d], acc[k]);
    if (d < K) atomicAdd(&pcnt[g * K + d], c);
}

// ---------------------------------------------------------------------------
// Stage 4: pocket_emb = (psum / (pcnt + 1e-9)) @ Wv + bv
// ---------------------------------------------------------------------------
__global__ __launch_bounds__(128) void pocket_emb_kernel(
    const float* __restrict__ psum, const float* __restrict__ pcnt,
    const float* __restrict__ Wv, const float* __restrict__ bv,
    float* __restrict__ pemb)
{
    __shared__ float smean[K * D];
    __shared__ float scnt[K];
    const int g = blockIdx.x;
    const int d = threadIdx.x;
    if (d < K) scnt[d] = pcnt[g * K + d];
    __syncthreads();
    #pragma unroll
    for (int k = 0; k < K; ++k)
        smean[k * D + d] = psum[(size_t)g * (K * D) + k * D + d] / (scnt[k] + 1e-9f);
    __syncthreads();

    float acc[K];
    const float bvv = bv[d];
    #pragma unroll
    for (int k = 0; k < K; ++k) acc[k] = bvv;
    for (int j = 0; j < D; ++j) {
        const float w = Wv[j * D + d];
        #pragma unroll
        for (int k = 0; k < K; ++k) acc[k] += smean[k * D + j] * w;
    }
    #pragma unroll
    for (int k = 0; k < K; ++k)
        pemb[(size_t)g * (K * D) + k * D + d] = acc[k];
}

// ---------------------------------------------------------------------------
// Stage 5: feedback gather + LayerNorm + ReLU. One wave per node.
// ---------------------------------------------------------------------------
__global__ __launch_bounds__(256) void ln_kernel(
    const float* __restrict__ xres, const float* __restrict__ pmask,
    const int* __restrict__ batch, const float* __restrict__ pemb,
    const float* __restrict__ gamma, const float* __restrict__ beta,
    float* __restrict__ out, int N)
{
    const int wave = threadIdx.x >> 6;
    const int lane = threadIdx.x & 63;
    const int n = blockIdx.x * 4 + wave;
    if (n >= N) return;
    const int d = lane * 2;

    float2 v = *(const float2*)(xres + (size_t)n * D + d);
    const int g = batch[n];
    const float* pe = pemb + (size_t)g * (K * D);
    const float4 m0 = *(const float4*)(pmask + (size_t)n * K);
    const float4 m1 = *(const float4*)(pmask + (size_t)n * K + 4);
    const float mk[K] = {m0.x, m0.y, m0.z, m0.w, m1.x, m1.y, m1.z, m1.w};
    #pragma unroll
    for (int k = 0; k < K; ++k) {
        if (mk[k] != 0.0f) {   // wave-uniform branch
            const float2 p = *(const float2*)(pe + k * D + d);
            v.x += mk[k] * p.x;
            v.y += mk[k] * p.y;
        }
    }

    float s = v.x + v.y;
    #pragma unroll
    for (int off = 32; off; off >>= 1) s += __shfl_xor(s, off, 64);
    const float mu = s * (1.0f / 128.0f);
    const float d0 = v.x - mu, d1 = v.y - mu;
    float sq = d0 * d0 + d1 * d1;
    #pragma unroll
    for (int off = 32; off; off >>= 1) sq += __shfl_xor(sq, off, 64);
    const float var = sq * (1.0f / 128.0f);
    const float inv = rsqrtf(var + 1e-5f);

    const float2 gm = *(const float2*)(gamma + d);
    const float2 bt = *(const float2*)(beta + d);
    float y0 = d0 * inv * gm.x + bt.x;
    float y1 = d1 * inv * gm.y + bt.y;
    y0 = y0 > 0.0f ? y0 : 0.0f;
    y1 = y1 > 0.0f ? y1 : 0.0f;
    *(float2*)(out + (size_t)n * D + d) = make_float2(y0, y1);
}

// ---------------------------------------------------------------------------
extern "C" void kernel_launch(void* const* d_in, const int* in_sizes, int n_in,
                              void* d_out, int out_size, void* d_ws, size_t ws_size,
                              hipStream_t stream)
{
    const float* x     = (const float*)d_in[0];
    const int*   ei    = (const int*)  d_in[1];
    const float* ea    = (const float*)d_in[2];
    const float* pmask = (const float*)d_in[3];
    const int*   batch = (const int*)  d_in[4];
    const float* We    = (const float*)d_in[5];
    const float* be    = (const float*)d_in[6];
    const float* W1    = (const float*)d_in[7];
    const float* b1    = (const float*)d_in[8];
    const float* W2    = (const float*)d_in[9];
    const float* b2    = (const float*)d_in[10];
    const float* epsp  = (const float*)d_in[11];
    const float* gamma = (const float*)d_in[12];
    const float* beta  = (const float*)d_in[13];
    const float* Wv    = (const float*)d_in[14];
    const float* bv    = (const float*)d_in[15];
    float* out = (float*)d_out;

    const int N = in_sizes[0] / D;     // 50000
    const int E = in_sizes[1] / 2;     // 600000
    const int* src = ei;
    const int* dst = ei + E;

    // Workspace: [deg | agg | psum | pcnt] (single memset), xres (aliased
    // below), pemb, scan scratch, xb (bf16 x), wb1t/wb2t/webt.
    int*   deg  = (int*)d_ws;                           // N
    float* agg  = (float*)(deg + N);                    // N*D
    float* psum = agg + (size_t)N * D;                  // B*K*D
    float* pcnt = psum + (size_t)BGRAPH * K * D;        // B*K
    float* xres = pcnt + (size_t)BGRAPH * K;            // N*D
    float* pemb = xres + (size_t)N * D;                 // B*K*D
    float* extra = pemb + (size_t)BGRAPH * K * D;       // scan scratch (128)
    __hip_bfloat16* xb = (__hip_bfloat16*)(extra + 128);// N*D bf16
    short* wb1t = (short*)(xb + (size_t)N * D);         // D*D bf16
    short* wb2t = wb1t + (size_t)D * D;                 // D*D bf16
    short* webt = wb2t + (size_t)D * D;                 // 2*128*32 bf16 (8K shorts)

    // Aliased inside xres region (cursor 0.2MB + md 4.8MB = 5MB < 25.6MB);
    // all consumed before mlp writes xres.
    int*   cursor = (int*)xres;                         // N
    uint2* md  = (uint2*)(((uintptr_t)(cursor + N) + 15) & ~(uintptr_t)15); // E

    int*  bsum  = (int*)extra;                          // 64
    int*  boffs = bsum + 64;                            // 64

    const int nb = (N + 1023) / 1024;                   // scan blocks (49)
    const int nchunks = (E + CH - 1) / CH;              // 9375
    const int NX = N * D;
    const int NBX = NX / 2048;                          // 3125 (exact)
    const int NBW = (2 * D * D + 2 * 128 * 32) / 256;   // 160 (exact)
    const int NBH = (E / 4 + 255) / 256;                // 586

    const size_t zero_bytes =
        ((size_t)N + (size_t)N * D + (size_t)BGRAPH * K * D + BGRAPH * K) * sizeof(float);
    hipMemsetAsync(d_ws, 0, zero_bytes, stream);

    prep_kernel<<<NBX + NBW + NBH, 256, 0, stream>>>(
        x, W1, W2, We, be, dst, xb, wb1t, wb2t, webt, deg,
        NX, E, NBX, NBW);
    scan_partial_kernel<<<nb, 256, 0, stream>>>(deg, bsum, N);
    scan_top_kernel<<<1, 64, 0, stream>>>(bsum, boffs, nb);
    scan_final_kernel<<<nb, 256, 0, stream>>>(deg, boffs, cursor, N);
    scatter_kernel<<<(E + 255) / 256, 256, 0, stream>>>(src, dst, cursor, md, E);
    gine_reduce_kernel<<<(nchunks + 3) / 4, 256, 0, stream>>>(
        xb, md, ea, webt, agg, E);

    mlp_mfma_kernel<<<(N + MROWS - 1) / MROWS, 256, 0, stream>>>(
        x, agg, epsp, wb1t, b1, wb2t, b2, xres, N);
    pocket_sum_kernel<<<BGRAPH * PPARTS, 128, 0, stream>>>(
        xres, pmask, batch, psum, pcnt, N);
    pocket_emb_kernel<<<BGRAPH, 128, 0, stream>>>(psum, pcnt, Wv, bv, pemb);
    ln_kernel<<<(N + 3) / 4, 256, 0, stream>>>(
        xres, pmask, batch, pemb, gamma, beta, out, N);
}

// Round 5
// 349.383 us; speedup vs baseline: 1.0784x; 1.0262x over previous
//
#include <hip/hip_runtime.h>
#include <hip/hip_bf16.h>
#include <stdint.h>

#define D 128
#define K 8
#define BGRAPH 64
#define CH 64    // edges per wave in gine_reduce
#define GRP 4    // edges per inner group

typedef __attribute__((ext_vector_type(8))) short bf16x8;
typedef __attribute__((ext_vector_type(4))) float f32x4;
typedef __attribute__((ext_vector_type(2))) float f32x2;

__device__ __forceinline__ short f2bf(float f) {
    union { float f; uint32_t u; } v; v.f = f;
    const uint32_t r = (v.u + 0x7fffu + ((v.u >> 16) & 1u)) >> 16;
    return (short)r;
}
__device__ __forceinline__ float bflo(uint32_t u) {
    union { uint32_t u; float f; } v; v.u = u << 16; return v.f;
}
__device__ __forceinline__ float bfhi(uint32_t u) {
    union { uint32_t u; float f; } v; v.u = u & 0xffff0000u; return v.f;
}

// ---------------------------------------------------------------------------
// Stage 0 (fused prep): cast x->bf16, W1/W2->bf16 transposed, We^T hi/lo bf16
// (K padded to 32, bias row at k=16), dst in-degree hist. (ea conversion now
// lives in scatter_kernel, which reads it coalesced.)
// ---------------------------------------------------------------------------
__global__ __launch_bounds__(256) void prep_kernel(
    const float* __restrict__ x,
    const float* __restrict__ W1, const float* __restrict__ W2,
    const float* __restrict__ We, const float* __restrict__ be,
    const int* __restrict__ dst,
    __hip_bfloat16* __restrict__ xb,
    short* __restrict__ wb1t, short* __restrict__ wb2t,
    short* __restrict__ webt,
    int* __restrict__ deg,
    int NX, int E, int NBX, int NBW)
{
    const int b = blockIdx.x;
    const int t = threadIdx.x;
    if (b < NBX) {
        // ---- cast x (8 floats/thread) ----
        const int i = b * 2048 + t * 8;
        if (i + 8 <= NX) {
            const float4 a = *(const float4*)(x + i);
            const float4 c = *(const float4*)(x + i + 4);
            short v[8];
            v[0] = f2bf(a.x); v[1] = f2bf(a.y); v[2] = f2bf(a.z); v[3] = f2bf(a.w);
            v[4] = f2bf(c.x); v[5] = f2bf(c.y); v[6] = f2bf(c.z); v[7] = f2bf(c.w);
            *(uint4*)((short*)xb + i) = *(const uint4*)v;
        }
    } else if (b < NBX + NBW) {
        const int idx = (b - NBX) * 256 + t;
        if (idx < 2 * D * D) {
            // ---- W1/W2 transpose cast (1 elem/thread) ----
            const int which = idx >> 14;           // 0: W1, 1: W2
            const int rem = idx & 16383;
            const int n = rem >> 7;
            const int k = rem & 127;
            const float* W = which ? W2 : W1;
            short* O = which ? wb2t : wb1t;
            O[n * D + k] = f2bf(W[(size_t)k * D + n]);
        } else {
            // ---- webt[2][128][32]: We^T hi/lo bf16, bias row at k=16 ----
            const int widx = idx - 2 * D * D;      // 0..8191
            const int h = widx >> 12;              // 0 hi, 1 lo
            const int c = (widx >> 5) & 127;
            const int k = widx & 31;
            float val = 0.f;
            if (k < 16) val = We[k * D + c];
            else if (k == 16) val = be[c];
            const short hi = f2bf(val);
            short outv;
            if (h == 0) outv = hi;
            else {
                union { uint32_t u; float f; } fh;
                fh.u = ((uint32_t)(unsigned short)hi) << 16;
                outv = f2bf(val - fh.f);
            }
            webt[(h << 12) + c * 32 + k] = outv;
        }
    } else {
        // ---- dst histogram (4 edges/thread) ----
        const int i = ((b - NBX - NBW) * 256 + t) * 4;
        if (i + 4 <= E) {
            const int4 v = *(const int4*)(dst + i);
            atomicAdd(&deg[v.x], 1);
            atomicAdd(&deg[v.y], 1);
            atomicAdd(&deg[v.z], 1);
            atomicAdd(&deg[v.w], 1);
        } else {
            for (int j = i; j < E; ++j) atomicAdd(&deg[dst[j]], 1);
        }
    }
}

// ---------------------------------------------------------------------------
// Stage 1b: three-phase exclusive scan of deg[N] -> cursor[N]
// ---------------------------------------------------------------------------
__global__ __launch_bounds__(256) void scan_partial_kernel(
    const int* __restrict__ deg, int* __restrict__ bsum, int N)
{
    const int t = threadIdx.x;
    const int base = (blockIdx.x * 256 + t) * 4;
    int s = 0;
    if (base + 4 <= N) {
        const int4 v = *(const int4*)(deg + base);
        s = v.x + v.y + v.z + v.w;
    } else {
        for (int j = base; j < N; ++j) s += deg[j];
    }
    __shared__ int red[256];
    red[t] = s;
    __syncthreads();
    for (int off = 128; off; off >>= 1) {
        if (t < off) red[t] += red[t + off];
        __syncthreads();
    }
    if (t == 0) bsum[blockIdx.x] = red[0];
}

__global__ __launch_bounds__(64) void scan_top_kernel(
    const int* __restrict__ bsum, int* __restrict__ boffs, int nb)
{
    __shared__ int sh[64];
    const int t = threadIdx.x;
    const int v = (t < nb) ? bsum[t] : 0;
    sh[t] = v;
    __syncthreads();
    for (int off = 1; off < 64; off <<= 1) {
        const int u = (t >= off) ? sh[t - off] : 0;
        __syncthreads();
        sh[t] += u;
        __syncthreads();
    }
    if (t < nb) boffs[t] = sh[t] - v;      // exclusive
}

__global__ __launch_bounds__(256) void scan_final_kernel(
    const int* __restrict__ deg, const int* __restrict__ boffs,
    int* __restrict__ cursor, int N)
{
    const int t = threadIdx.x;
    const int base = (blockIdx.x * 256 + t) * 4;
    int v0 = 0, v1 = 0, v2 = 0, v3 = 0;
    if (base + 4 <= N) {
        const int4 v = *(const int4*)(deg + base);
        v0 = v.x; v1 = v.y; v2 = v.z; v3 = v.w;
    } else {
        if (base     < N) v0 = deg[base];
        if (base + 1 < N) v1 = deg[base + 1];
        if (base + 2 < N) v2 = deg[base + 2];
        if (base + 3 < N) v3 = deg[base + 3];
    }
    const int s = v0 + v1 + v2 + v3;
    __shared__ int sh[256];
    sh[t] = s;
    __syncthreads();
    for (int off = 1; off < 256; off <<= 1) {
        const int u = (t >= off) ? sh[t - off] : 0;
        __syncthreads();
        sh[t] += u;
        __syncthreads();
    }
    int ex = boffs[blockIdx.x] + sh[t] - s;
    if (base < N)     { cursor[base]     = ex; } ex += v0;
    if (base + 1 < N) { cursor[base + 1] = ex; } ex += v1;
    if (base + 2 < N) { cursor[base + 2] = ex; } ex += v2;
    if (base + 3 < N) { cursor[base + 3] = ex; }
}

// ---------------------------------------------------------------------------
// Stage 1c: scatter packed (src|dst<<16) into dst-grouped order AND
// materialize the bf16 ea row at its sorted position (coalesced ea read,
// scattered 32B write — off any critical read path).
// ---------------------------------------------------------------------------
__global__ __launch_bounds__(256) void scatter_kernel(
    const int* __restrict__ src, const int* __restrict__ dst,
    const float* __restrict__ ea,
    int* __restrict__ cursor, uint2* __restrict__ md,
    short* __restrict__ eabs, int E)
{
    const int i = blockIdx.x * 256 + threadIdx.x;
    if (i < E) {
        const unsigned sv = (unsigned)src[i];
        const unsigned dv = (unsigned)dst[i];
        const int p = atomicAdd(&cursor[dv], 1);
        md[p] = make_uint2(sv | (dv << 16), (unsigned)i);
        const float4* ep = (const float4*)(ea + (size_t)i * 16);
        const float4 a = ep[0], b = ep[1], c = ep[2], e4 = ep[3];
        short v[16];
        v[0]  = f2bf(a.x);  v[1]  = f2bf(a.y);  v[2]  = f2bf(a.z);  v[3]  = f2bf(a.w);
        v[4]  = f2bf(b.x);  v[5]  = f2bf(b.y);  v[6]  = f2bf(b.z);  v[7]  = f2bf(b.w);
        v[8]  = f2bf(c.x);  v[9]  = f2bf(c.y);  v[10] = f2bf(c.z);  v[11] = f2bf(c.w);
        v[12] = f2bf(e4.x); v[13] = f2bf(e4.y); v[14] = f2bf(e4.z); v[15] = f2bf(e4.w);
        uint4* op = (uint4*)(eabs + (size_t)p * 16);
        op[0] = *(const uint4*)v;
        op[1] = *(const uint4*)(v + 8);
    }
}

// ---------------------------------------------------------------------------
// Stage 1d: edge-parallel gather-reduce (R3 structure). ea@We+be on the MFMA
// pipe: per 16-edge mgroup, A = dst-sorted bf16 ea rows read STREAMING by
// position (no indirection); K padded to 32 with bias row 1.0 at k=16;
// B = We^T bf16 hi/lo. C -> wave-private 16x132 LDS tile; serial consume
// reads eemb rows from LDS. md 3-deep, x 2-deep pipeline.
// ---------------------------------------------------------------------------
__device__ __forceinline__ void flush_row(
    float* __restrict__ agg, int node, int d, f32x2 acc, int first, int last)
{
    float* p = agg + (size_t)node * D + d;
    if (node == first || node == last) {
        if (acc.x != 0.f) atomicAdd(p,     acc.x);
        if (acc.y != 0.f) atomicAdd(p + 1, acc.y);
    } else {
        *(f32x2*)p = acc;
    }
}

__global__ __launch_bounds__(256) void gine_reduce_kernel(
    const __hip_bfloat16* __restrict__ xb, const uint2* __restrict__ md,
    const short* __restrict__ eabs, const short* __restrict__ webt,
    float* __restrict__ agg, int E)
{
    __shared__ float lsh[4][16 * 132];   // 33.8 KB, wave-private tiles
    const int wave = threadIdx.x >> 6;
    const int lane = threadIdx.x & 63;
    const int chunk = __builtin_amdgcn_readfirstlane(blockIdx.x * 4 + wave);
    const int e0 = chunk * CH;
    if (e0 >= E) return;
    const int d = lane * 2;
    const int m = lane & 15;
    const int q = lane >> 4;
    float* myl = lsh[wave];
    const int NG = CH / GRP;                       // 16

    // B fragments: col = ct*16+m, k = q*8..q*8+7 (hi and lo tables)
    bf16x8 bH[8], bL[8];
    #pragma unroll
    for (int ct = 0; ct < 8; ++ct) {
        bH[ct] = *(const bf16x8*)(webt +        (ct * 16 + m) * 32 + q * 8);
        bL[ct] = *(const bf16x8*)(webt + 4096 + (ct * 16 + m) * 32 + q * 8);
    }

    // A fragment for mgroup 0: STREAMING read at sorted position e0+m.
    uint4 afcur = *(const uint4*)(eabs + (size_t)(e0 + m) * 16 + (q & 1) * 8);

    // scalar md pipeline + x prefetch (GRP granularity)
    uint2 ma[GRP], mb[GRP], mc[GRP];
    #pragma unroll
    for (int j = 0; j < GRP; ++j) ma[j] = md[e0 + j];
    #pragma unroll
    for (int j = 0; j < GRP; ++j) mb[j] = md[e0 + GRP + j];
    #pragma unroll
    for (int j = 0; j < GRP; ++j) mc[j] = md[e0 + 2 * GRP + j];

    uint32_t xcur[GRP], xn1[GRP];
    #pragma unroll
    for (int j = 0; j < GRP; ++j)
        xcur[j] = *(const uint32_t*)(xb + (size_t)(ma[j].x & 0xffffu) * D + d);
    #pragma unroll
    for (int j = 0; j < GRP; ++j)
        xn1[j] = *(const uint32_t*)(xb + (size_t)(mb[j].x & 0xffffu) * D + d);

    const int first = (int)(ma[0].x >> 16);
    const int last  = (int)(md[e0 + CH - 1].x >> 16);

    f32x2 acc = {0.f, 0.f};
    int cur = first;

    for (int g = 0; g < NG; ++g) {
        if ((g & 3) == 0) {
            // ---- MFMA block for mgroup mg; streaming prefetch A for mg+1 ----
            const int mg = g >> 2;
            uint4 afn = make_uint4(0u, 0u, 0u, 0u);
            if (mg < 3)
                afn = *(const uint4*)(eabs +
                    (size_t)(e0 + (mg + 1) * 16 + m) * 16 + (q & 1) * 8);
            uint4 au = afcur;
            if (q >= 2)
                au = make_uint4(q == 2 ? 0x3f80u : 0u, 0u, 0u, 0u); // k16 = 1.0
            const bf16x8 a = *(const bf16x8*)&au;
            f32x4 mm[8];
            #pragma unroll
            for (int ct = 0; ct < 8; ++ct) {
                const f32x4 z = {0.f, 0.f, 0.f, 0.f};
                mm[ct] = __builtin_amdgcn_mfma_f32_16x16x32_bf16(a, bL[ct], z, 0, 0, 0);
            }
            #pragma unroll
            for (int ct = 0; ct < 8; ++ct)
                mm[ct] = __builtin_amdgcn_mfma_f32_16x16x32_bf16(a, bH[ct], mm[ct], 0, 0, 0);
            // C: edge row = q*4+r, col = ct*16+m  (stride 132: conflict-free)
            #pragma unroll
            for (int ct = 0; ct < 8; ++ct)
                #pragma unroll
                for (int r = 0; r < 4; ++r)
                    myl[(q * 4 + r) * 132 + ct * 16 + m] = mm[ct][r];
            afcur = afn;
        }

        // prefetch: meta g+3, x g+2
        uint2 mnn[GRP] = {};
        uint32_t xn2[GRP] = {};
        if (g + 3 < NG) {
            #pragma unroll
            for (int j = 0; j < GRP; ++j) mnn[j] = md[e0 + (g + 3) * GRP + j];
        }
        if (g + 2 < NG) {
            #pragma unroll
            for (int j = 0; j < GRP; ++j)
                xn2[j] = *(const uint32_t*)(xb + (size_t)(mc[j].x & 0xffffu) * D + d);
        }

        #pragma unroll
        for (int j = 0; j < GRP; ++j) {
            const int dk = (int)(ma[j].x >> 16);
            if (dk != cur) {                  // wave-uniform scalar branch
                flush_row(agg, cur, d, acc, first, last);
                acc.x = 0.f; acc.y = 0.f;
                cur = dk;
            }
            const uint32_t xu = xcur[j];
            const float2 em = *(const float2*)(myl + ((g & 3) * GRP + j) * 132 + d);
            const float v0 = em.x + bflo(xu);
            const float v1 = em.y + bfhi(xu);
            acc.x += v0 > 0.f ? v0 : 0.f;
            acc.y += v1 > 0.f ? v1 : 0.f;
        }

        #pragma unroll
        for (int j = 0; j < GRP; ++j) {
            ma[j] = mb[j]; mb[j] = mc[j]; mc[j] = mnn[j];
            xcur[j] = xn1[j]; xn1[j] = xn2[j];
        }
    }
    flush_row(agg, cur, d, acc, first, last);
}

// ---------------------------------------------------------------------------
// Stage 2: MFMA MLP.  x_res = relu(h@W1+b1)@W2+b2,  h = (1+eps)*x + agg.
// Block = 64 rows, 4 waves; wave owns 16 rows; t overwrites h in place.
// ---------------------------------------------------------------------------
#define MROWS 64
#define HSTR  132
__global__ __launch_bounds__(256) void mlp_mfma_kernel(
    const float* __restrict__ x, const float* __restrict__ agg,
    const float* __restrict__ epsp,
    const short* __restrict__ wb1t, const float* __restrict__ b1,
    const short* __restrict__ wb2t, const float* __restrict__ b2,
    float* __restrict__ xres, int N)
{
    __shared__ float hsh[MROWS * HSTR];   // 33.8 KB
    const int row0 = blockIdx.x * MROWS;
    const float ep = 1.0f + epsp[0];

    for (int i = threadIdx.x; i < MROWS * D / 4; i += 256) {
        const int flat = i * 4;
        const int r = flat >> 7;
        const int c = flat & (D - 1);
        const int row = row0 + r;
        float4 hv = make_float4(0.f, 0.f, 0.f, 0.f);
        if (row < N) {
            const float4 xv = *(const float4*)(x   + (size_t)row * D + c);
            const float4 av = *(const float4*)(agg + (size_t)row * D + c);
            hv = make_float4(ep * xv.x + av.x, ep * xv.y + av.y,
                             ep * xv.z + av.z, ep * xv.w + av.w);
        }
        *(float4*)(hsh + r * HSTR + c) = hv;
    }
    __syncthreads();

    const int lane = threadIdx.x & 63;
    const int wrow = (threadIdx.x >> 6) * 16;  // wave's 16-row window
    const int m = lane & 15;
    const int q = lane >> 4;

    f32x4 acc[8];

    // ---- layer 1 ----
    #pragma unroll
    for (int ct = 0; ct < 8; ++ct) {
        const float b = b1[ct * 16 + m];
        acc[ct] = (f32x4){b, b, b, b};
    }
    #pragma unroll
    for (int ks = 0; ks < 4; ++ks) {
        const float* ap = hsh + (wrow + m) * HSTR + ks * 32 + q * 8;
        float av[8];
        *(float4*)(av)     = *(const float4*)ap;
        *(float4*)(av + 4) = *(const float4*)(ap + 4);
        bf16x8 a;
        #pragma unroll
        for (int j = 0; j < 8; ++j) a[j] = f2bf(av[j]);
        #pragma unroll
        for (int ct = 0; ct < 8; ++ct) {
            const bf16x8 b = *(const bf16x8*)(wb1t + (ct * 16 + m) * D + ks * 32 + q * 8);
            acc[ct] = __builtin_amdgcn_mfma_f32_16x16x32_bf16(a, b, acc[ct], 0, 0, 0);
        }
    }
    #pragma unroll
    for (int ct = 0; ct < 8; ++ct)
        #pragma unroll
        for (int r = 0; r < 4; ++r) {
            const float v = acc[ct][r];
            hsh[(wrow + q * 4 + r) * HSTR + ct * 16 + m] = v > 0.f ? v : 0.f;
        }

    // ---- layer 2 ----
    #pragma unroll
    for (int ct = 0; ct < 8; ++ct) {
        const float b = b2[ct * 16 + m];
        acc[ct] = (f32x4){b, b, b, b};
    }
    #pragma unroll
    for (int ks = 0; ks < 4; ++ks) {
        const float* ap = hsh + (wrow + m) * HSTR + ks * 32 + q * 8;
        float av[8];
        *(float4*)(av)     = *(const float4*)ap;
        *(float4*)(av + 4) = *(const float4*)(ap + 4);
        bf16x8 a;
        #pragma unroll
        for (int j = 0; j < 8; ++j) a[j] = f2bf(av[j]);
        #pragma unroll
        for (int ct = 0; ct < 8; ++ct) {
            const bf16x8 b = *(const bf16x8*)(wb2t + (ct * 16 + m) * D + ks * 32 + q * 8);
            acc[ct] = __builtin_amdgcn_mfma_f32_16x16x32_bf16(a, b, acc[ct], 0, 0, 0);
        }
    }
    #pragma unroll
    for (int r = 0; r < 4; ++r) {
        const int row = row0 + wrow + q * 4 + r;
        if (row < N) {
            #pragma unroll
            for (int ct = 0; ct < 8; ++ct)
                xres[(size_t)row * D + ct * 16 + m] = acc[ct][r];
        }
    }
}

// ---------------------------------------------------------------------------
// Stage 3: per-(graph,pocket) masked sums
// ---------------------------------------------------------------------------
#define PPARTS 32
__global__ __launch_bounds__(128) void pocket_sum_kernel(
    const float* __restrict__ xres, const float* __restrict__ pmask,
    const int* __restrict__ batch,
    float* __restrict__ psum, float* __restrict__ pcnt, int N)
{
    const int g = blockIdx.x / PPARTS;
    const int part = blockIdx.x % PPARTS;

    int lo, hi;
    {
        int l = 0, r = N;
        while (l < r) { int m = (l + r) >> 1; if (batch[m] < g) l = m + 1; else r = m; }
        lo = l;
        r = N;
        while (l < r) { int m = (l + r) >> 1; if (batch[m] < g + 1) l = m + 1; else r = m; }
        hi = l;
    }
    const int cnt = hi - lo;
    const int per = (cnt + PPARTS - 1) / PPARTS;
    const int s = lo + part * per;
    const int e = min(s + per, hi);

    const int d = threadIdx.x;
    float acc[K];
    #pragma unroll
    for (int k = 0; k < K; ++k) acc[k] = 0.0f;
    float c = 0.0f;

    for (int n = s; n < e; ++n) {
        const float xv = xres[(size_t)n * D + d];
        const float4 m0 = *(const float4*)(pmask + (size_t)n * K);
        const float4 m1 = *(const float4*)(pmask + (size_t)n * K + 4);
        acc[0] += m0.x * xv; acc[1] += m0.y * xv;
        acc[2] += m0.z * xv; acc[3] += m0.w * xv;
        acc[4] += m1.x * xv; acc[5] += m1.y * xv;
        acc[6] += m1.z * xv; acc[7] += m1.w * xv;
        if (d < K) c += pmask[(size_t)n * K + d];
    }
    #pragma unroll
    for (int k = 0; k < K; ++k)
        atomicAdd(&psum[(size_t)g * (K * D) + k * D + d], acc[k]);
    if (d < K) atomicAdd(&pcnt[g * K + d], c);
}

// ---------------------------------------------------------------------------
// Stage 4: pocket_emb = (psum / (pcnt + 1e-9)) @ Wv + bv
// ---------------------------------------------------------------------------
__global__ __launch_bounds__(128) void pocket_emb_kernel(
    const float* __restrict__ psum, const float* __restrict__ pcnt,
    const float* __restrict__ Wv, const float* __restrict__ bv,
    float* __restrict__ pemb)
{
    __shared__ float smean[K * D];
    __shared__ float scnt[K];
    const int g = blockIdx.x;
    const int d = threadIdx.x;
    if (d < K) scnt[d] = pcnt[g * K + d];
    __syncthreads();
    #pragma unroll
    for (int k = 0; k < K; ++k)
        smean[k * D + d] = psum[(size_t)g * (K * D) + k * D + d] / (scnt[k] + 1e-9f);
    __syncthreads();

    float acc[K];
    const float bvv = bv[d];
    #pragma unroll
    for (int k = 0; k < K; ++k) acc[k] = bvv;
    for (int j = 0; j < D; ++j) {
        const float w = Wv[j * D + d];
        #pragma unroll
        for (int k = 0; k < K; ++k) acc[k] += smean[k * D + j] * w;
    }
    #pragma unroll
    for (int k = 0; k < K; ++k)
        pemb[(size_t)g * (K * D) + k * D + d] = acc[k];
}

// ---------------------------------------------------------------------------
// Stage 5: feedback gather + LayerNorm + ReLU. One wave per node.
// ---------------------------------------------------------------------------
__global__ __launch_bounds__(256) void ln_kernel(
    const float* __restrict__ xres, const float* __restrict__ pmask,
    const int* __restrict__ batch, const float* __restrict__ pemb,
    const float* __restrict__ gamma, const float* __restrict__ beta,
    float* __restrict__ out, int N)
{
    const int wave = threadIdx.x >> 6;
    const int lane = threadIdx.x & 63;
    const int n = blockIdx.x * 4 + wave;
    if (n >= N) return;
    const int d = lane * 2;

    float2 v = *(const float2*)(xres + (size_t)n * D + d);
    const int g = batch[n];
    const float* pe = pemb + (size_t)g * (K * D);
    const float4 m0 = *(const float4*)(pmask + (size_t)n * K);
    const float4 m1 = *(const float4*)(pmask + (size_t)n * K + 4);
    const float mk[K] = {m0.x, m0.y, m0.z, m0.w, m1.x, m1.y, m1.z, m1.w};
    #pragma unroll
    for (int k = 0; k < K; ++k) {
        if (mk[k] != 0.0f) {   // wave-uniform branch
            const float2 p = *(const float2*)(pe + k * D + d);
            v.x += mk[k] * p.x;
            v.y += mk[k] * p.y;
        }
    }

    float s = v.x + v.y;
    #pragma unroll
    for (int off = 32; off; off >>= 1) s += __shfl_xor(s, off, 64);
    const float mu = s * (1.0f / 128.0f);
    const float d0 = v.x - mu, d1 = v.y - mu;
    float sq = d0 * d0 + d1 * d1;
    #pragma unroll
    for (int off = 32; off; off >>= 1) sq += __shfl_xor(sq, off, 64);
    const float var = sq * (1.0f / 128.0f);
    const float inv = rsqrtf(var + 1e-5f);

    const float2 gm = *(const float2*)(gamma + d);
    const float2 bt = *(const float2*)(beta + d);
    float y0 = d0 * inv * gm.x + bt.x;
    float y1 = d1 * inv * gm.y + bt.y;
    y0 = y0 > 0.0f ? y0 : 0.0f;
    y1 = y1 > 0.0f ? y1 : 0.0f;
    *(float2*)(out + (size_t)n * D + d) = make_float2(y0, y1);
}

// ---------------------------------------------------------------------------
extern "C" void kernel_launch(void* const* d_in, const int* in_sizes, int n_in,
                              void* d_out, int out_size, void* d_ws, size_t ws_size,
                              hipStream_t stream)
{
    const float* x     = (const float*)d_in[0];
    const int*   ei    = (const int*)  d_in[1];
    const float* ea    = (const float*)d_in[2];
    const float* pmask = (const float*)d_in[3];
    const int*   batch = (const int*)  d_in[4];
    const float* We    = (const float*)d_in[5];
    const float* be    = (const float*)d_in[6];
    const float* W1    = (const float*)d_in[7];
    const float* b1    = (const float*)d_in[8];
    const float* W2    = (const float*)d_in[9];
    const float* b2    = (const float*)d_in[10];
    const float* epsp  = (const float*)d_in[11];
    const float* gamma = (const float*)d_in[12];
    const float* beta  = (const float*)d_in[13];
    const float* Wv    = (const float*)d_in[14];
    const float* bv    = (const float*)d_in[15];
    float* out = (float*)d_out;

    const int N = in_sizes[0] / D;     // 50000
    const int E = in_sizes[1] / 2;     // 600000
    const int* src = ei;
    const int* dst = ei + E;

    // Workspace: [deg | agg | psum | pcnt] (single memset), xres (aliased
    // below), pemb, scan scratch, xb (bf16 x), wb1t/wb2t/webt.
    int*   deg  = (int*)d_ws;                           // N
    float* agg  = (float*)(deg + N);                    // N*D
    float* psum = agg + (size_t)N * D;                  // B*K*D
    float* pcnt = psum + (size_t)BGRAPH * K * D;        // B*K
    float* xres = pcnt + (size_t)BGRAPH * K;            // N*D
    float* pemb = xres + (size_t)N * D;                 // B*K*D
    float* extra = pemb + (size_t)BGRAPH * K * D;       // scan scratch (128)
    __hip_bfloat16* xb = (__hip_bfloat16*)(extra + 128);// N*D bf16
    short* wb1t = (short*)(xb + (size_t)N * D);         // D*D bf16
    short* wb2t = wb1t + (size_t)D * D;                 // D*D bf16
    short* webt = wb2t + (size_t)D * D;                 // 2*128*32 bf16 (8K shorts)

    // Aliased inside xres region (cursor 0.2MB + md 4.8MB + eabs 19.2MB
    // = 24.2MB < 25.6MB); all consumed before mlp writes xres.
    int*   cursor = (int*)xres;                         // N
    uint2* md  = (uint2*)(((uintptr_t)(cursor + N) + 15) & ~(uintptr_t)15); // E
    short* eabs = (short*)(md + E);                     // E*16 bf16, sorted order

    int*  bsum  = (int*)extra;                          // 64
    int*  boffs = bsum + 64;                            // 64

    const int nb = (N + 1023) / 1024;                   // scan blocks (49)
    const int nchunks = (E + CH - 1) / CH;              // 9375
    const int NX = N * D;
    const int NBX = NX / 2048;                          // 3125 (exact)
    const int NBW = (2 * D * D + 2 * 128 * 32) / 256;   // 160 (exact)
    const int NBH = (E / 4 + 255) / 256;                // 586

    const size_t zero_bytes =
        ((size_t)N + (size_t)N * D + (size_t)BGRAPH * K * D + BGRAPH * K) * sizeof(float);
    hipMemsetAsync(d_ws, 0, zero_bytes, stream);

    prep_kernel<<<NBX + NBW + NBH, 256, 0, stream>>>(
        x, W1, W2, We, be, dst, xb, wb1t, wb2t, webt, deg,
        NX, E, NBX, NBW);
    scan_partial_kernel<<<nb, 256, 0, stream>>>(deg, bsum, N);
    scan_top_kernel<<<1, 64, 0, stream>>>(bsum, boffs, nb);
    scan_final_kernel<<<nb, 256, 0, stream>>>(deg, boffs, cursor, N);
    scatter_kernel<<<(E + 255) / 256, 256, 0, stream>>>(
        src, dst, ea, cursor, md, eabs, E);
    gine_reduce_kernel<<<(nchunks + 3) / 4, 256, 0, stream>>>(
        xb, md, eabs, webt, agg, E);

    mlp_mfma_kernel<<<(N + MROWS - 1) / MROWS, 256, 0, stream>>>(
        x, agg, epsp, wb1t, b1, wb2t, b2, xres, N);
    pocket_sum_kernel<<<BGRAPH * PPARTS, 128, 0, stream>>>(
        xres, pmask, batch, psum, pcnt, N);
    pocket_emb_kernel<<<BGRAPH, 128, 0, stream>>>(psum, pcnt, Wv, bv, pemb);
    ln_kernel<<<(N + 3) / 4, 256, 0, stream>>>(
        xres, pmask, batch, pemb, gamma, beta, out, N);
}